// Round 8
// baseline (1502.306 us; speedup 1.0000x reference)
//
#include <hip/hip_runtime.h>

// Problem constants (match reference setup_inputs)
#define D 64
constexpr int Pn  = 100000;
constexpr int Un  = 20000;
constexpr int Rn  = 1000;
constexpr int Cn  = 500;
constexpr int Tn  = 50;
constexpr int Bn  = 4096;
constexpr int ETn = 50000;
constexpr int NNZ_COL = 1000000;
constexpr int NNZ_REG = 300000;
constexpr int NNZ_CAT = 300000;
constexpr int NNZ_T   = 1000000;
constexpr int TILE = 8192;   // elements per scatter/hist block

static inline int cdiv(int a, int b) { return (a + b - 1) / b; }

__device__ __forceinline__ unsigned short f2bf(float f) {
  unsigned u = __float_as_uint(f);
  unsigned r = (u + 0x7FFF + ((u >> 16) & 1)) >> 16;  // round-to-nearest-even
  return (unsigned short)r;
}
__device__ __forceinline__ float bf2f(unsigned short h) {
  return __uint_as_float((unsigned)h << 16);
}

// ---------------------------------------------------------------------------
// gate: out = x * sigmoid(x @ W + b); writes f32 Pout + f32 Aout (+ optional
// bf16 mirror of Pout for gather consumers).
// ---------------------------------------------------------------------------
__global__ __launch_bounds__(256) void gate_kernel(
    const float* __restrict__ Xin, const float* __restrict__ W,
    const float* __restrict__ bias, float* __restrict__ Pout,
    float* __restrict__ Aout, unsigned short* __restrict__ P16, int N) {
  __shared__ float sx[4][D];
  int tid = threadIdx.x, wv = tid >> 6, lane = tid & 63;
  float wcol[D];
#pragma unroll
  for (int k = 0; k < D; ++k) wcol[k] = W[k * D + lane];
  float bl = bias[lane];
  for (int row = blockIdx.x * 4 + wv; row < N; row += gridDim.x * 4) {
    float x = Xin[row * D + lane];
    sx[wv][lane] = x;
    float y = 0.f;
#pragma unroll
    for (int k = 0; k < D; ++k) y += sx[wv][k] * wcol[k];
    float s = 1.f / (1.f + __expf(-(y + bl)));
    float o = x * s;
    Pout[row * D + lane] = o;
    Aout[row * D + lane] = o;
    if (P16) P16[row * D + lane] = f2bf(o);
  }
}

// Y(f32) = X @ W  (tiny, for We@Wf_bot)
__global__ __launch_bounds__(256) void matmul_kernel(
    const float* __restrict__ Xin, const float* __restrict__ W,
    float* __restrict__ Y, int N) {
  __shared__ float sx[4][D];
  int tid = threadIdx.x, wv = tid >> 6, lane = tid & 63;
  float wcol[D];
#pragma unroll
  for (int k = 0; k < D; ++k) wcol[k] = W[k * D + lane];
  for (int row = blockIdx.x * 4 + wv; row < N; row += gridDim.x * 4) {
    sx[wv][lane] = Xin[row * D + lane];
    float y = 0.f;
#pragma unroll
    for (int k = 0; k < D; ++k) y += sx[wv][k] * wcol[k];
    Y[row * D + lane] = y;
  }
}

// Y(bf16) = X @ W  (gather-source tables)
__global__ __launch_bounds__(256) void matmul_bf16_kernel(
    const float* __restrict__ Xin, const float* __restrict__ W,
    unsigned short* __restrict__ Y, int N) {
  __shared__ float sx[4][D];
  int tid = threadIdx.x, wv = tid >> 6, lane = tid & 63;
  float wcol[D];
#pragma unroll
  for (int k = 0; k < D; ++k) wcol[k] = W[k * D + lane];
  for (int row = blockIdx.x * 4 + wv; row < N; row += gridDim.x * 4) {
    sx[wv][lane] = Xin[row * D + lane];
    float y = 0.f;
#pragma unroll
    for (int k = 0; k < D; ++k) y += sx[wv][k] * wcol[k];
    Y[row * D + lane] = f2bf(y);
  }
}

// fused hetero edge update + residual:
// fused = A@W1 + e_buf@W2 ; fusedOut16 = bf16(fused);
// e_buf += fused ; accE += e_buf(new)
__global__ __launch_bounds__(256) void fused2_resid_kernel(
    const float* __restrict__ A, const float* __restrict__ W1,
    const float* __restrict__ W2, unsigned short* __restrict__ fusedOut16,
    float* __restrict__ e_buf, float* __restrict__ accE, int N) {
  __shared__ float sa[4][D], sb2[4][D];
  int tid = threadIdx.x, wv = tid >> 6, lane = tid & 63;
  float w1[D], w2[D];
#pragma unroll
  for (int k = 0; k < D; ++k) {
    w1[k] = W1[k * D + lane];
    w2[k] = W2[k * D + lane];
  }
  for (int row = blockIdx.x * 4 + wv; row < N; row += gridDim.x * 4) {
    sa[wv][lane]  = A[row * D + lane];
    float eo = e_buf[row * D + lane];
    sb2[wv][lane] = eo;
    float y = 0.f;
#pragma unroll
    for (int k = 0; k < D; ++k) y += sa[wv][k] * w1[k] + sb2[wv][k] * w2[k];
    fusedOut16[row * D + lane] = f2bf(y);
    float en = eo + y;
    e_buf[row * D + lane] = en;
    accE[row * D + lane] += en;
  }
}

// ---------------------------------------------------------------------------
// LDS-privatized bucket histogram. Bucket space: dir1 key>>s1 in [0,nb1),
// dir2 key>>7 offset by nb1. nk = total buckets (<= 2047).
// ---------------------------------------------------------------------------
__global__ __launch_bounds__(256) void hist_binned_kernel(
    const int* __restrict__ k1, const int* __restrict__ k2,
    int* __restrict__ counts, int s1, int nb1, int nk, int nnz) {
  extern __shared__ int lh[];
  int tid = threadIdx.x;
  for (int k = tid; k < nk; k += 256) lh[k] = 0;
  __syncthreads();
  int t0 = blockIdx.x * TILE, t1 = min(t0 + TILE, nnz);
  for (int i = t0 + tid; i < t1; i += 256) {
    atomicAdd(&lh[k1[i] >> s1], 1);
    atomicAdd(&lh[nb1 + (k2[i] >> 7)], 1);
  }
  __syncthreads();
  for (int k = tid; k < nk; k += 256) {
    int c = lh[k];
    if (c) atomicAdd(&counts[k], c);
  }
}

// single-block exclusive scan over n <= 4096 bucket counts; dual output
// (bktptr stays pristine for refine; cursorB is mutated by scatter).
__global__ __launch_bounds__(1024) void scan_dual_kernel(
    const int* __restrict__ in, int* __restrict__ bktptr,
    int* __restrict__ cursorB, int n) {
  __shared__ int lds[16];
  int tid = threadIdx.x, lane = tid & 63, wv = tid >> 6;
  int x[4];
  int s = 0;
#pragma unroll
  for (int e = 0; e < 4; ++e) {
    int i = tid * 4 + e;
    x[e] = (i < n) ? in[i] : 0;
    s += x[e];
  }
  int sc = s;
#pragma unroll
  for (int d = 1; d < 64; d <<= 1) {
    int y = __shfl_up(sc, d);
    if (lane >= d) sc += y;
  }
  if (lane == 63) lds[wv] = sc;
  __syncthreads();
  if (tid < 16) {
    int w = lds[tid];
#pragma unroll
    for (int d = 1; d < 16; d <<= 1) {
      int y = __shfl_up(w, d);
      if (lane >= d) w += y;
    }
    lds[tid] = w;
  }
  __syncthreads();
  int woff = (wv == 0) ? 0 : lds[wv - 1];
  int excl = woff + sc - s;
#pragma unroll
  for (int e = 0; e < 4; ++e) {
    int i = tid * 4 + e;
    if (i < n) {
      bktptr[i] = excl;
      cursorB[i] = excl;
    }
    excl += x[e];
  }
}

// LDS-binned scatter into bucket-grouped layout (line-friendly runs).
// Payload .x = (row_local << 17) | other_idx.
__global__ __launch_bounds__(256) void scatter_binned_kernel(
    const int* __restrict__ k1, const int* __restrict__ o1,
    const float* __restrict__ v1, const int* __restrict__ k2,
    const int* __restrict__ o2, const float* __restrict__ v2,
    int* __restrict__ cursorB, int2* __restrict__ sd, int s1, int nb1, int nk,
    int nnz) {
  extern __shared__ int ls[];  // [0,nk)=cnt, [nk,2nk)=base
  int* cnt = ls;
  int* bas = ls + nk;
  int tid = threadIdx.x;
  for (int k = tid; k < nk; k += 256) cnt[k] = 0;
  __syncthreads();
  int t0 = blockIdx.x * TILE, t1 = min(t0 + TILE, nnz);
  for (int i = t0 + tid; i < t1; i += 256) {
    atomicAdd(&cnt[k1[i] >> s1], 1);
    atomicAdd(&cnt[nb1 + (k2[i] >> 7)], 1);
  }
  __syncthreads();
  for (int k = tid; k < nk; k += 256) {
    int c = cnt[k];
    bas[k] = c ? atomicAdd(&cursorB[k], c) : 0;
  }
  __syncthreads();
  for (int k = tid; k < nk; k += 256) cnt[k] = 0;
  __syncthreads();
  int m1 = (1 << s1) - 1;
  for (int i = t0 + tid; i < t1; i += 256) {
    int r1 = k1[i], key1 = r1 >> s1;
    int off1 = atomicAdd(&cnt[key1], 1);
    sd[bas[key1] + off1] =
        make_int2(((r1 & m1) << 17) | o1[i], __float_as_int(v1[i]));
    int r2 = k2[i], key2 = nb1 + (r2 >> 7);
    int off2 = atomicAdd(&cnt[key2], 1);
    sd[bas[key2] + off2] =
        make_int2(((r2 & 127) << 17) | o2[i], __float_as_int(v2[i]));
  }
}

// ---------------------------------------------------------------------------
// Refine: bucket-grouped -> exact row-grouped IN PLACE, and WRITE exact
// rowptr (bucket_start + within-bucket exclusive row offsets). Block per
// bucket; <=4096 elems staged in registers (static idx). rows==1 buckets
// (exact already): just write rowptr, skip reorder.
// ---------------------------------------------------------------------------
__global__ __launch_bounds__(256) void refine_kernel(
    const int* __restrict__ bktptr, int2* __restrict__ sd,
    int* __restrict__ rowptr, int s1, int nb1, int nk1, int nkb, int tot) {
  __shared__ int cnt[128];
  __shared__ int wsum[2];
  int tid = threadIdx.x, b = blockIdx.x;
  int sft, row0, kbase, klim;
  if (b < nb1) {
    sft = s1; row0 = b << s1; kbase = 0; klim = nk1;
  } else {
    sft = 7; row0 = (b - nb1) << 7; kbase = nk1; klim = Pn;
  }
  int rows = min(1 << sft, klim - row0);
  int bstart = bktptr[b];
  int bend = (b + 1 < nkb) ? bktptr[b + 1] : tot;
  if (rows == 1) {
    if (tid == 0) rowptr[kbase + row0] = bstart;
    return;
  }
  if (tid < rows) cnt[tid] = 0;
  __syncthreads();
  int2 st[16];
#pragma unroll
  for (int j = 0; j < 16; ++j) {
    int i = bstart + tid + (j << 8);
    st[j] = (i < bend) ? sd[i] : make_int2(0, 0);
  }
#pragma unroll
  for (int j = 0; j < 16; ++j) {
    int i = bstart + tid + (j << 8);
    if (i < bend) atomicAdd(&cnt[st[j].x >> 17], 1);
  }
  __syncthreads();
  // exclusive scan of cnt[0..rows) by threads 0..127 (2 waves)
  int v = 0, sc = 0;
  if (tid < 128) {
    v = (tid < rows) ? cnt[tid] : 0;
    sc = v;
    int lane = tid & 63;
#pragma unroll
    for (int d = 1; d < 64; d <<= 1) {
      int y = __shfl_up(sc, d);
      if (lane >= d) sc += y;
    }
    if (lane == 63) wsum[tid >> 6] = sc;
  }
  __syncthreads();
  int excl = sc - v + ((tid >= 64 && tid < 128) ? wsum[0] : 0);
  __syncthreads();  // cnt reads done before overwrite
  if (tid < rows) {
    rowptr[kbase + row0 + tid] = bstart + excl;
    cnt[tid] = excl;  // becomes placement cursor
  }
  __syncthreads();
#pragma unroll
  for (int j = 0; j < 16; ++j) {
    int i = bstart + tid + (j << 8);
    if (i < bend) {
      int r = st[j].x >> 17;
      int dst = bstart + atomicAdd(&cnt[r], 1);
      sd[dst] = st[j];
    }
  }
}

// ---------------------------------------------------------------------------
// Exact-CSR SpMM, wave per row (64 lanes), bf16 gather source, unroll-4.
// Output modes: fused residual (presid/acc f32 + optional bf16 mirror) or
// plain write (f32 Yf, or bf16 Y16).
// ---------------------------------------------------------------------------
__global__ __launch_bounds__(256) void spmm_csr_kernel(
    const int* __restrict__ rowptr, int base, int nkx, int tot,
    const int2* __restrict__ sd, const unsigned short* __restrict__ X16,
    float* __restrict__ Yf, unsigned short* __restrict__ Y16,
    float* __restrict__ presid, float* __restrict__ acc,
    unsigned short* __restrict__ pm16, int nrows) {
  int lane = threadIdx.x & 63;
  int w = (int)((blockIdx.x * (long)blockDim.x + threadIdx.x) >> 6);
  if (w >= nrows) return;
  int idx = base + w;
  int start = rowptr[idx];
  int end = (idx + 1 == nkx) ? tot : rowptr[idx + 1];
  float a0 = 0.f, a1 = 0.f, a2 = 0.f, a3 = 0.f;
  int n = start;
  for (; n + 4 <= end; n += 4) {
    int2 c0 = sd[n], c1 = sd[n + 1], c2 = sd[n + 2], c3 = sd[n + 3];
    float x0 = bf2f(X16[(size_t)(c0.x & 0x1FFFF) * D + lane]);
    float x1 = bf2f(X16[(size_t)(c1.x & 0x1FFFF) * D + lane]);
    float x2 = bf2f(X16[(size_t)(c2.x & 0x1FFFF) * D + lane]);
    float x3 = bf2f(X16[(size_t)(c3.x & 0x1FFFF) * D + lane]);
    a0 += __int_as_float(c0.y) * x0;
    a1 += __int_as_float(c1.y) * x1;
    a2 += __int_as_float(c2.y) * x2;
    a3 += __int_as_float(c3.y) * x3;
  }
  for (; n < end; ++n) {
    int2 cv = sd[n];
    a0 += __int_as_float(cv.y) * bf2f(X16[(size_t)(cv.x & 0x1FFFF) * D + lane]);
  }
  float y = (a0 + a1) + (a2 + a3);
  size_t o = (size_t)w * D + lane;
  if (presid) {
    float p = presid[o] + y;
    presid[o] = p;
    acc[o] += p;
    if (pm16) pm16[o] = f2bf(p);
  } else if (Y16) {
    Y16[o] = f2bf(y);
  } else {
    Yf[o] = y;
  }
}

// a = src; b = src  (float4)
__global__ __launch_bounds__(256) void copy2_kernel(
    const float4* __restrict__ s, float4* __restrict__ a,
    float4* __restrict__ b, int n4) {
  int i = blockIdx.x * blockDim.x + threadIdx.x;
  if (i < n4) {
    float4 v = s[i];
    a[i] = v;
    b[i] = v;
  }
}

// Final pooling: masked mean over T of 4 padded tables + user add, scale 1/3.
__global__ __launch_bounds__(256) void final_kernel(
    const int* __restrict__ user_idx, const int* __restrict__ seq,
    const int* __restrict__ mask, const float* __restrict__ colP,
    const float* __restrict__ transP, const float* __restrict__ regP,
    const float* __restrict__ catP, const float* __restrict__ colU,
    float* __restrict__ out) {
  int wid = (int)((blockIdx.x * blockDim.x + threadIdx.x) >> 6);
  int lane = threadIdx.x & 63;
  if (wid >= Bn) return;
  float sc = 0.f, st = 0.f, sr = 0.f, sca = 0.f;
  int cnt = 0;
  for (int t = 0; t < Tn; ++t) {
    int m = mask[wid * Tn + t];
    int idx = seq[wid * Tn + t];
    cnt += m;
    if (m && idx < Pn) {
      sc  += colP[idx * D + lane];
      st  += transP[idx * D + lane];
      sr  += regP[idx * D + lane];
      sca += catP[idx * D + lane];
    }
  }
  float dn = 1.f / (float)(cnt > 0 ? cnt : 1);
  const float inv = 1.f / 3.f;  // 1/(N_LAYERS+1), common to all four nets
  int u = user_idx[wid];
  out[0 * Bn * D + wid * D + lane] = (colU[u * D + lane] + sc * dn) * inv;
  out[1 * Bn * D + wid * D + lane] = st * dn * inv;
  out[2 * Bn * D + wid * D + lane] = sr * dn * inv;
  out[3 * Bn * D + wid * D + lane] = sca * dn * inv;
}

extern "C" void kernel_launch(void* const* d_in, const int* in_sizes, int n_in,
                              void* d_out, int out_size, void* d_ws,
                              size_t ws_size, hipStream_t stream) {
  (void)in_sizes; (void)n_in; (void)out_size; (void)ws_size;
  const int*   user_idx      = (const int*)d_in[0];
  const int*   user_seq      = (const int*)d_in[1];
  const int*   user_seq_mask = (const int*)d_in[2];
  const int*   col_poi_idx   = (const int*)d_in[3];
  const int*   col_user_idx  = (const int*)d_in[4];
  const float* col_vals_pe   = (const float*)d_in[5];
  const float* col_vals_ep   = (const float*)d_in[6];
  const int*   reg_poi_idx   = (const int*)d_in[7];
  const int*   reg_region_idx= (const int*)d_in[8];
  const float* reg_vals_pe   = (const float*)d_in[9];
  const float* reg_vals_ep   = (const float*)d_in[10];
  const int*   cat_poi_idx   = (const int*)d_in[11];
  const int*   cat_cat_idx   = (const int*)d_in[12];
  const float* cat_vals_pe   = (const float*)d_in[13];
  const float* cat_vals_ep   = (const float*)d_in[14];
  const int*   trans_poi_idx = (const int*)d_in[15];
  const int*   trans_edge_idx= (const int*)d_in[16];
  const float* trans_vals_tar= (const float*)d_in[17];
  const float* trans_vals_src= (const float*)d_in[18];
  const float* poi_emb       = (const float*)d_in[19];
  const float* user_emb      = (const float*)d_in[20];
  const float* region_emb    = (const float*)d_in[21];
  const float* cat_emb       = (const float*)d_in[22];
  const float* w_gate_col    = (const float*)d_in[23];
  const float* b_gate_col    = (const float*)d_in[24];
  const float* w_gate_trans  = (const float*)d_in[25];
  const float* b_gate_trans  = (const float*)d_in[26];
  const float* w_gate_reg    = (const float*)d_in[27];
  const float* b_gate_reg    = (const float*)d_in[28];
  const float* w_gate_cat    = (const float*)d_in[29];
  const float* b_gate_cat    = (const float*)d_in[30];
  const float* col_Wp = (const float*)d_in[31];
  const float* col_We = (const float*)d_in[32];
  const float* col_Wf = (const float*)d_in[33];
  const float* reg_Wp = (const float*)d_in[34];
  const float* reg_We = (const float*)d_in[35];
  const float* reg_Wf = (const float*)d_in[36];
  const float* cat_Wp = (const float*)d_in[37];
  const float* cat_We = (const float*)d_in[38];
  const float* cat_Wf = (const float*)d_in[39];

  float* ws = (float*)d_ws;
  size_t off = 0;
  auto alloc = [&](size_t n) { float* p = ws + off; off += n; return p; };
  const size_t PD = (size_t)Pn * D;
  const size_t UD = (size_t)Un * D;
  const size_t ED = (size_t)ETn * D;

  float* colP   = alloc(PD);
  float* regP   = alloc(PD);
  float* catP   = alloc(PD);
  float* transP = alloc(PD);
  float* colU   = alloc(UD);
  float* p_buf  = alloc(PD);
  float* e_buf  = alloc(UD);
  float* tmpE1  = alloc(UD);              // hetero pe-spmm out (f32, <=Un rows)
  float* acce   = alloc((size_t)Rn * D);
  float* WeWf   = alloc(D * D);
  unsigned short* tmpP16   = (unsigned short*)alloc(PD / 2);  // bf16 gather src
  unsigned short* tmpE2_16 = (unsigned short*)alloc(UD / 2);
  unsigned short* tmpE1_16 = (unsigned short*)alloc(ED / 2);  // trans hop1 out
  unsigned short* p16      = (unsigned short*)alloc(PD / 2);  // trans p mirror
  int2*  sd     = (int2*)alloc(4 * (size_t)NNZ_T);  // both dirs, 2*nnz int2
  int*   rowptr = (int*)alloc(Pn + ETn + 2);
  int*   bktcnt = (int*)alloc(4096);
  int*   bktptr = (int*)alloc(4096);
  int*   cursorB= (int*)alloc(4096);

  const int GCAP = 1024;
  const int NB2 = cdiv(Pn, 128);  // 782 poi buckets (shift 7)

  // Build exact CSR (both directions) for one graph:
  // bucket-hist (LDS) -> 1-block scan -> binned scatter -> refine (writes
  // exact rowptr + reorders in place).
  auto sort2 = [&](const int* k1, const int* o1, const float* v1, int s1,
                   int nk1, const int* k2, const int* o2, const float* v2,
                   int nnz) {
    int nb1 = cdiv(nk1, 1 << s1);
    int nkb = nb1 + NB2;                 // bucket count (<= ~1800)
    int tot = 2 * nnz;
    hipMemsetAsync(bktcnt, 0, (size_t)nkb * sizeof(int), stream);
    int nblk = cdiv(nnz, TILE);
    hist_binned_kernel<<<nblk, 256, nkb * 4, stream>>>(k1, k2, bktcnt, s1, nb1,
                                                       nkb, nnz);
    scan_dual_kernel<<<1, 1024, 0, stream>>>(bktcnt, bktptr, cursorB, nkb);
    scatter_binned_kernel<<<nblk, 256, 2 * nkb * 4, stream>>>(
        k1, o1, v1, k2, o2, v2, cursorB, sd, s1, nb1, nkb, nnz);
    refine_kernel<<<nkb, 256, 0, stream>>>(bktptr, sd, rowptr, s1, nb1, nk1,
                                           nkb, tot);
    return nk1 + Pn;  // exact key count
  };

  auto spmm = [&](int base, int nkx, int nnz2, const unsigned short* X16,
                  float* Yf, unsigned short* Y16, float* presid, float* acc,
                  unsigned short* pm16, int nrows) {
    spmm_csr_kernel<<<cdiv(nrows, 4), 256, 0, stream>>>(
        rowptr, base, nkx, nnz2, sd, X16, Yf, Y16, presid, acc, pm16, nrows);
  };

  auto hetero = [&](const float* wg, const float* bg, const float* edge_emb,
                    int Ne, int s1, const int* poi_idx, const int* edge_idx,
                    const float* v_pe, const float* v_ep, const float* Wp,
                    const float* We, const float* Wf, int nnz, float* accP,
                    float* accE) {
    int nkx = sort2(edge_idx, poi_idx, v_pe, s1, Ne, poi_idx, edge_idx, v_ep,
                    nnz);
    gate_kernel<<<GCAP, 256, 0, stream>>>(poi_emb, wg, bg, p_buf, accP,
                                          nullptr, Pn);
    copy2_kernel<<<cdiv(Ne * D / 4, 256), 256, 0, stream>>>(
        (const float4*)edge_emb, (float4*)e_buf, (float4*)accE, Ne * D / 4);
    matmul_kernel<<<16, 256, 0, stream>>>(We, Wf + D * D, WeWf, D);  // We@Wf_bot
    for (int l = 0; l < 2; ++l) {
      matmul_bf16_kernel<<<GCAP, 256, 0, stream>>>(p_buf, Wp, tmpP16, Pn);
      spmm(0, nkx, 2 * nnz, tmpP16, tmpE1, nullptr, nullptr, nullptr, nullptr,
           Ne);  // poi_msg (dest=edge rows)
      fused2_resid_kernel<<<min(cdiv(Ne, 4), GCAP), 256, 0, stream>>>(
          tmpE1, Wf, WeWf, tmpE2_16, e_buf, accE, Ne);
      spmm(Ne, nkx, 2 * nnz, tmpE2_16, nullptr, nullptr, p_buf, accP, nullptr,
           Pn);  // prop + fused residual
    }
  };

  // --- three hetero nets (acc scaled by 1/3 in final kernel) ---
  hetero(w_gate_col, b_gate_col, user_emb, Un, 5, col_poi_idx, col_user_idx,
         col_vals_pe, col_vals_ep, col_Wp, col_We, col_Wf, NNZ_COL, colP, colU);
  hetero(w_gate_reg, b_gate_reg, region_emb, Rn, 0, reg_poi_idx,
         reg_region_idx, reg_vals_pe, reg_vals_ep, reg_Wp, reg_We, reg_Wf,
         NNZ_REG, regP, acce);
  hetero(w_gate_cat, b_gate_cat, cat_emb, Cn, 0, cat_poi_idx, cat_cat_idx,
         cat_vals_pe, cat_vals_ep, cat_Wp, cat_We, cat_Wf, NNZ_CAT, catP, acce);

  // --- directed trans net (bf16 mirror p16 is the gather source) ---
  int nkx = sort2(trans_edge_idx, trans_poi_idx, trans_vals_tar, 6, ETn,
                  trans_poi_idx, trans_edge_idx, trans_vals_src, NNZ_T);
  gate_kernel<<<GCAP, 256, 0, stream>>>(poi_emb, w_gate_trans, b_gate_trans,
                                        p_buf, transP, p16, Pn);
  for (int l = 0; l < 2; ++l) {
    spmm(0, nkx, 2 * NNZ_T, p16, nullptr, tmpE1_16, nullptr, nullptr, nullptr,
         ETn);  // msg_tar -> bf16
    spmm(ETn, nkx, 2 * NNZ_T, tmpE1_16, nullptr, nullptr, p_buf, transP, p16,
         Pn);   // msg_src + residual + mirror update
  }

  // --- sequence pooling + output ---
  final_kernel<<<cdiv(Bn * 64, 256), 256, 0, stream>>>(
      user_idx, user_seq, user_seq_mask, colP, transP, regP, catP, colU,
      (float*)d_out);
}

// Round 9
// 1332.343 us; speedup vs baseline: 1.1276x; 1.1276x over previous
//
#include <hip/hip_runtime.h>

// Problem constants (match reference setup_inputs)
#define D 64
constexpr int Pn  = 100000;
constexpr int Un  = 20000;
constexpr int Rn  = 1000;
constexpr int Cn  = 500;
constexpr int Tn  = 50;
constexpr int Bn  = 4096;
constexpr int ETn = 50000;
constexpr int NNZ_COL = 1000000;
constexpr int NNZ_REG = 300000;
constexpr int NNZ_CAT = 300000;
constexpr int NNZ_T   = 1000000;
constexpr int TILE = 8192;   // elements per scatter/hist block

static inline int cdiv(int a, int b) { return (a + b - 1) / b; }

__device__ __forceinline__ unsigned short f2bf(float f) {
  unsigned u = __float_as_uint(f);
  unsigned r = (u + 0x7FFF + ((u >> 16) & 1)) >> 16;  // round-to-nearest-even
  return (unsigned short)r;
}
__device__ __forceinline__ float bf2f(unsigned short h) {
  return __uint_as_float((unsigned)h << 16);
}
__device__ __forceinline__ float bflo(unsigned d) {
  return __uint_as_float(d << 16);
}
__device__ __forceinline__ float bfhi(unsigned d) {
  return __uint_as_float(d & 0xFFFF0000u);
}

// ---------------------------------------------------------------------------
// gate: out = x * sigmoid(x @ W + b); writes f32 Pout + f32 Aout (+ optional
// bf16 mirror of Pout for gather consumers).
// ---------------------------------------------------------------------------
__global__ __launch_bounds__(256) void gate_kernel(
    const float* __restrict__ Xin, const float* __restrict__ W,
    const float* __restrict__ bias, float* __restrict__ Pout,
    float* __restrict__ Aout, unsigned short* __restrict__ P16, int N) {
  __shared__ float sx[4][D];
  int tid = threadIdx.x, wv = tid >> 6, lane = tid & 63;
  float wcol[D];
#pragma unroll
  for (int k = 0; k < D; ++k) wcol[k] = W[k * D + lane];
  float bl = bias[lane];
  for (int row = blockIdx.x * 4 + wv; row < N; row += gridDim.x * 4) {
    float x = Xin[row * D + lane];
    sx[wv][lane] = x;
    float y = 0.f;
#pragma unroll
    for (int k = 0; k < D; ++k) y += sx[wv][k] * wcol[k];
    float s = 1.f / (1.f + __expf(-(y + bl)));
    float o = x * s;
    Pout[row * D + lane] = o;
    Aout[row * D + lane] = o;
    if (P16) P16[row * D + lane] = f2bf(o);
  }
}

// Y(f32) = X @ W  (tiny, for We@Wf_bot)
__global__ __launch_bounds__(256) void matmul_kernel(
    const float* __restrict__ Xin, const float* __restrict__ W,
    float* __restrict__ Y, int N) {
  __shared__ float sx[4][D];
  int tid = threadIdx.x, wv = tid >> 6, lane = tid & 63;
  float wcol[D];
#pragma unroll
  for (int k = 0; k < D; ++k) wcol[k] = W[k * D + lane];
  for (int row = blockIdx.x * 4 + wv; row < N; row += gridDim.x * 4) {
    sx[wv][lane] = Xin[row * D + lane];
    float y = 0.f;
#pragma unroll
    for (int k = 0; k < D; ++k) y += sx[wv][k] * wcol[k];
    Y[row * D + lane] = y;
  }
}

// Y(bf16) = X @ W  (gather-source tables)
__global__ __launch_bounds__(256) void matmul_bf16_kernel(
    const float* __restrict__ Xin, const float* __restrict__ W,
    unsigned short* __restrict__ Y, int N) {
  __shared__ float sx[4][D];
  int tid = threadIdx.x, wv = tid >> 6, lane = tid & 63;
  float wcol[D];
#pragma unroll
  for (int k = 0; k < D; ++k) wcol[k] = W[k * D + lane];
  for (int row = blockIdx.x * 4 + wv; row < N; row += gridDim.x * 4) {
    sx[wv][lane] = Xin[row * D + lane];
    float y = 0.f;
#pragma unroll
    for (int k = 0; k < D; ++k) y += sx[wv][k] * wcol[k];
    Y[row * D + lane] = f2bf(y);
  }
}

// fused hetero edge update + residual:
// fused = A@W1 + e_buf@W2 ; fusedOut16 = bf16(fused);
// e_buf += fused ; accE += e_buf(new)
__global__ __launch_bounds__(256) void fused2_resid_kernel(
    const float* __restrict__ A, const float* __restrict__ W1,
    const float* __restrict__ W2, unsigned short* __restrict__ fusedOut16,
    float* __restrict__ e_buf, float* __restrict__ accE, int N) {
  __shared__ float sa[4][D], sb2[4][D];
  int tid = threadIdx.x, wv = tid >> 6, lane = tid & 63;
  float w1[D], w2[D];
#pragma unroll
  for (int k = 0; k < D; ++k) {
    w1[k] = W1[k * D + lane];
    w2[k] = W2[k * D + lane];
  }
  for (int row = blockIdx.x * 4 + wv; row < N; row += gridDim.x * 4) {
    sa[wv][lane]  = A[row * D + lane];
    float eo = e_buf[row * D + lane];
    sb2[wv][lane] = eo;
    float y = 0.f;
#pragma unroll
    for (int k = 0; k < D; ++k) y += sa[wv][k] * w1[k] + sb2[wv][k] * w2[k];
    fusedOut16[row * D + lane] = f2bf(y);
    float en = eo + y;
    e_buf[row * D + lane] = en;
    accE[row * D + lane] += en;
  }
}

// ---------------------------------------------------------------------------
// LDS-privatized bucket histogram. Bucket space: dir1 key>>s1 in [0,nb1),
// dir2 key>>7 offset by nb1. nk = total buckets (<= 2047).
// ---------------------------------------------------------------------------
__global__ __launch_bounds__(256) void hist_binned_kernel(
    const int* __restrict__ k1, const int* __restrict__ k2,
    int* __restrict__ counts, int s1, int nb1, int nk, int nnz) {
  extern __shared__ int lh[];
  int tid = threadIdx.x;
  for (int k = tid; k < nk; k += 256) lh[k] = 0;
  __syncthreads();
  int t0 = blockIdx.x * TILE, t1 = min(t0 + TILE, nnz);
  for (int i = t0 + tid; i < t1; i += 256) {
    atomicAdd(&lh[k1[i] >> s1], 1);
    atomicAdd(&lh[nb1 + (k2[i] >> 7)], 1);
  }
  __syncthreads();
  for (int k = tid; k < nk; k += 256) {
    int c = lh[k];
    if (c) atomicAdd(&counts[k], c);
  }
}

// single-block exclusive scan over n <= 4096 bucket counts; dual output
// (bktptr stays pristine for refine; cursorB is mutated by scatter).
__global__ __launch_bounds__(1024) void scan_dual_kernel(
    const int* __restrict__ in, int* __restrict__ bktptr,
    int* __restrict__ cursorB, int n) {
  __shared__ int lds[16];
  int tid = threadIdx.x, lane = tid & 63, wv = tid >> 6;
  int x[4];
  int s = 0;
#pragma unroll
  for (int e = 0; e < 4; ++e) {
    int i = tid * 4 + e;
    x[e] = (i < n) ? in[i] : 0;
    s += x[e];
  }
  int sc = s;
#pragma unroll
  for (int d = 1; d < 64; d <<= 1) {
    int y = __shfl_up(sc, d);
    if (lane >= d) sc += y;
  }
  if (lane == 63) lds[wv] = sc;
  __syncthreads();
  if (tid < 16) {
    int w = lds[tid];
#pragma unroll
    for (int d = 1; d < 16; d <<= 1) {
      int y = __shfl_up(w, d);
      if (lane >= d) w += y;
    }
    lds[tid] = w;
  }
  __syncthreads();
  int woff = (wv == 0) ? 0 : lds[wv - 1];
  int excl = woff + sc - s;
#pragma unroll
  for (int e = 0; e < 4; ++e) {
    int i = tid * 4 + e;
    if (i < n) {
      bktptr[i] = excl;
      cursorB[i] = excl;
    }
    excl += x[e];
  }
}

// LDS-binned scatter into bucket-grouped layout (line-friendly runs).
// Payload .x = (row_local << 17) | other_idx.
__global__ __launch_bounds__(256) void scatter_binned_kernel(
    const int* __restrict__ k1, const int* __restrict__ o1,
    const float* __restrict__ v1, const int* __restrict__ k2,
    const int* __restrict__ o2, const float* __restrict__ v2,
    int* __restrict__ cursorB, int2* __restrict__ sd, int s1, int nb1, int nk,
    int nnz) {
  extern __shared__ int ls[];  // [0,nk)=cnt, [nk,2nk)=base
  int* cnt = ls;
  int* bas = ls + nk;
  int tid = threadIdx.x;
  for (int k = tid; k < nk; k += 256) cnt[k] = 0;
  __syncthreads();
  int t0 = blockIdx.x * TILE, t1 = min(t0 + TILE, nnz);
  for (int i = t0 + tid; i < t1; i += 256) {
    atomicAdd(&cnt[k1[i] >> s1], 1);
    atomicAdd(&cnt[nb1 + (k2[i] >> 7)], 1);
  }
  __syncthreads();
  for (int k = tid; k < nk; k += 256) {
    int c = cnt[k];
    bas[k] = c ? atomicAdd(&cursorB[k], c) : 0;
  }
  __syncthreads();
  for (int k = tid; k < nk; k += 256) cnt[k] = 0;
  __syncthreads();
  int m1 = (1 << s1) - 1;
  for (int i = t0 + tid; i < t1; i += 256) {
    int r1 = k1[i], key1 = r1 >> s1;
    int off1 = atomicAdd(&cnt[key1], 1);
    sd[bas[key1] + off1] =
        make_int2(((r1 & m1) << 17) | o1[i], __float_as_int(v1[i]));
    int r2 = k2[i], key2 = nb1 + (r2 >> 7);
    int off2 = atomicAdd(&cnt[key2], 1);
    sd[bas[key2] + off2] =
        make_int2(((r2 & 127) << 17) | o2[i], __float_as_int(v2[i]));
  }
}

// ---------------------------------------------------------------------------
// Refine: bucket-grouped -> exact row-grouped IN PLACE, and WRITE exact
// rowptr (bucket_start + within-bucket exclusive row offsets). Block per
// bucket; <=4096 elems staged in registers (static idx). rows==1 buckets
// (exact already): just write rowptr, skip reorder.
// ---------------------------------------------------------------------------
__global__ __launch_bounds__(256) void refine_kernel(
    const int* __restrict__ bktptr, int2* __restrict__ sd,
    int* __restrict__ rowptr, int s1, int nb1, int nk1, int nkb, int tot) {
  __shared__ int cnt[128];
  __shared__ int wsum[2];
  int tid = threadIdx.x, b = blockIdx.x;
  int sft, row0, kbase, klim;
  if (b < nb1) {
    sft = s1; row0 = b << s1; kbase = 0; klim = nk1;
  } else {
    sft = 7; row0 = (b - nb1) << 7; kbase = nk1; klim = Pn;
  }
  int rows = min(1 << sft, klim - row0);
  int bstart = bktptr[b];
  int bend = (b + 1 < nkb) ? bktptr[b + 1] : tot;
  if (rows == 1) {
    if (tid == 0) rowptr[kbase + row0] = bstart;
    return;
  }
  if (tid < rows) cnt[tid] = 0;
  __syncthreads();
  int2 st[16];
#pragma unroll
  for (int j = 0; j < 16; ++j) {
    int i = bstart + tid + (j << 8);
    st[j] = (i < bend) ? sd[i] : make_int2(0, 0);
  }
#pragma unroll
  for (int j = 0; j < 16; ++j) {
    int i = bstart + tid + (j << 8);
    if (i < bend) atomicAdd(&cnt[st[j].x >> 17], 1);
  }
  __syncthreads();
  // exclusive scan of cnt[0..rows) by threads 0..127 (2 waves)
  int v = 0, sc = 0;
  if (tid < 128) {
    v = (tid < rows) ? cnt[tid] : 0;
    sc = v;
    int lane = tid & 63;
#pragma unroll
    for (int d = 1; d < 64; d <<= 1) {
      int y = __shfl_up(sc, d);
      if (lane >= d) sc += y;
    }
    if (lane == 63) wsum[tid >> 6] = sc;
  }
  __syncthreads();
  int excl = sc - v + ((tid >= 64 && tid < 128) ? wsum[0] : 0);
  __syncthreads();  // cnt reads done before overwrite
  if (tid < rows) {
    rowptr[kbase + row0 + tid] = bstart + excl;
    cnt[tid] = excl;  // becomes placement cursor
  }
  __syncthreads();
#pragma unroll
  for (int j = 0; j < 16; ++j) {
    int i = bstart + tid + (j << 8);
    if (i < bend) {
      int r = st[j].x >> 17;
      int dst = bstart + atomicAdd(&cnt[r], 1);
      sd[dst] = st[j];
    }
  }
}

// ---------------------------------------------------------------------------
// Exact-CSR SpMM, wave per row, 2 nnz per gather instruction: lanes 0-31
// handle nnz n (32 dwords = 128B bf16 row), lanes 32-63 handle nnz n+1.
// Halves the gather instruction count vs 64-lane-per-row. Halves merged by
// one shfl(lane^32) at row end; epilogue by lanes 0-31 as float2/uint.
// ---------------------------------------------------------------------------
__global__ __launch_bounds__(256) void spmm_csr_kernel(
    const int* __restrict__ rowptr, int base, int nkx, int tot,
    const int2* __restrict__ sd, const unsigned* __restrict__ X32,
    float* __restrict__ Yf, unsigned* __restrict__ Y32,
    float* __restrict__ presid, float* __restrict__ acc,
    unsigned* __restrict__ pm32, int nrows) {
  int lane = threadIdx.x & 63;
  int half = lane >> 5, l5 = lane & 31;
  int w = (int)((blockIdx.x * (long)blockDim.x + threadIdx.x) >> 6);
  if (w >= nrows) return;
  int idx = base + w;
  int start = rowptr[idx];
  int end = (idx + 1 == nkx) ? tot : rowptr[idx + 1];
  float ax0 = 0.f, ay0 = 0.f, ax1 = 0.f, ay1 = 0.f;
  float ax2 = 0.f, ay2 = 0.f, ax3 = 0.f, ay3 = 0.f;
  int n = start + half;  // this half's nnz stream (stride 2)
  for (; n + 6 < end; n += 8) {
    int2 c0 = sd[n], c1 = sd[n + 2], c2 = sd[n + 4], c3 = sd[n + 6];
    unsigned d0 = X32[(size_t)(c0.x & 0x1FFFF) * 32 + l5];
    unsigned d1 = X32[(size_t)(c1.x & 0x1FFFF) * 32 + l5];
    unsigned d2 = X32[(size_t)(c2.x & 0x1FFFF) * 32 + l5];
    unsigned d3 = X32[(size_t)(c3.x & 0x1FFFF) * 32 + l5];
    float v0 = __int_as_float(c0.y), v1 = __int_as_float(c1.y);
    float v2 = __int_as_float(c2.y), v3 = __int_as_float(c3.y);
    ax0 += v0 * bflo(d0); ay0 += v0 * bfhi(d0);
    ax1 += v1 * bflo(d1); ay1 += v1 * bfhi(d1);
    ax2 += v2 * bflo(d2); ay2 += v2 * bfhi(d2);
    ax3 += v3 * bflo(d3); ay3 += v3 * bfhi(d3);
  }
  for (; n < end; n += 2) {
    int2 cv = sd[n];
    unsigned dv = X32[(size_t)(cv.x & 0x1FFFF) * 32 + l5];
    float vv = __int_as_float(cv.y);
    ax0 += vv * bflo(dv); ay0 += vv * bfhi(dv);
  }
  float yx = (ax0 + ax1) + (ax2 + ax3);
  float yy = (ay0 + ay1) + (ay2 + ay3);
  // merge halves (each lane adds the other half's partial for same row elems)
  yx += __shfl(yx, lane ^ 32);
  yy += __shfl(yy, lane ^ 32);
  if (half) return;
  // lanes 0-31: lane l5 holds row elements (2*l5, 2*l5+1)
  size_t o = (size_t)w * D + 2 * l5;
  if (presid) {
    float2 p = *(float2*)&presid[o];
    p.x += yx; p.y += yy;
    *(float2*)&presid[o] = p;
    float2 av = *(float2*)&acc[o];
    av.x += p.x; av.y += p.y;
    *(float2*)&acc[o] = av;
    if (pm32)
      pm32[(size_t)w * 32 + l5] = (unsigned)f2bf(p.x) | ((unsigned)f2bf(p.y) << 16);
  } else if (Y32) {
    Y32[(size_t)w * 32 + l5] = (unsigned)f2bf(yx) | ((unsigned)f2bf(yy) << 16);
  } else {
    float2 yv; yv.x = yx; yv.y = yy;
    *(float2*)&Yf[o] = yv;
  }
}

// a = src; b = src  (float4)
__global__ __launch_bounds__(256) void copy2_kernel(
    const float4* __restrict__ s, float4* __restrict__ a,
    float4* __restrict__ b, int n4) {
  int i = blockIdx.x * blockDim.x + threadIdx.x;
  if (i < n4) {
    float4 v = s[i];
    a[i] = v;
    b[i] = v;
  }
}

// Final pooling: masked mean over T of 4 padded tables + user add, scale 1/3.
__global__ __launch_bounds__(256) void final_kernel(
    const int* __restrict__ user_idx, const int* __restrict__ seq,
    const int* __restrict__ mask, const float* __restrict__ colP,
    const float* __restrict__ transP, const float* __restrict__ regP,
    const float* __restrict__ catP, const float* __restrict__ colU,
    float* __restrict__ out) {
  int wid = (int)((blockIdx.x * blockDim.x + threadIdx.x) >> 6);
  int lane = threadIdx.x & 63;
  if (wid >= Bn) return;
  float sc = 0.f, st = 0.f, sr = 0.f, sca = 0.f;
  int cnt = 0;
  for (int t = 0; t < Tn; ++t) {
    int m = mask[wid * Tn + t];
    int idx = seq[wid * Tn + t];
    cnt += m;
    if (m && idx < Pn) {
      sc  += colP[idx * D + lane];
      st  += transP[idx * D + lane];
      sr  += regP[idx * D + lane];
      sca += catP[idx * D + lane];
    }
  }
  float dn = 1.f / (float)(cnt > 0 ? cnt : 1);
  const float inv = 1.f / 3.f;  // 1/(N_LAYERS+1), common to all four nets
  int u = user_idx[wid];
  out[0 * Bn * D + wid * D + lane] = (colU[u * D + lane] + sc * dn) * inv;
  out[1 * Bn * D + wid * D + lane] = st * dn * inv;
  out[2 * Bn * D + wid * D + lane] = sr * dn * inv;
  out[3 * Bn * D + wid * D + lane] = sca * dn * inv;
}

extern "C" void kernel_launch(void* const* d_in, const int* in_sizes, int n_in,
                              void* d_out, int out_size, void* d_ws,
                              size_t ws_size, hipStream_t stream) {
  (void)in_sizes; (void)n_in; (void)out_size; (void)ws_size;
  const int*   user_idx      = (const int*)d_in[0];
  const int*   user_seq      = (const int*)d_in[1];
  const int*   user_seq_mask = (const int*)d_in[2];
  const int*   col_poi_idx   = (const int*)d_in[3];
  const int*   col_user_idx  = (const int*)d_in[4];
  const float* col_vals_pe   = (const float*)d_in[5];
  const float* col_vals_ep   = (const float*)d_in[6];
  const int*   reg_poi_idx   = (const int*)d_in[7];
  const int*   reg_region_idx= (const int*)d_in[8];
  const float* reg_vals_pe   = (const float*)d_in[9];
  const float* reg_vals_ep   = (const float*)d_in[10];
  const int*   cat_poi_idx   = (const int*)d_in[11];
  const int*   cat_cat_idx   = (const int*)d_in[12];
  const float* cat_vals_pe   = (const float*)d_in[13];
  const float* cat_vals_ep   = (const float*)d_in[14];
  const int*   trans_poi_idx = (const int*)d_in[15];
  const int*   trans_edge_idx= (const int*)d_in[16];
  const float* trans_vals_tar= (const float*)d_in[17];
  const float* trans_vals_src= (const float*)d_in[18];
  const float* poi_emb       = (const float*)d_in[19];
  const float* user_emb      = (const float*)d_in[20];
  const float* region_emb    = (const float*)d_in[21];
  const float* cat_emb       = (const float*)d_in[22];
  const float* w_gate_col    = (const float*)d_in[23];
  const float* b_gate_col    = (const float*)d_in[24];
  const float* w_gate_trans  = (const float*)d_in[25];
  const float* b_gate_trans  = (const float*)d_in[26];
  const float* w_gate_reg    = (const float*)d_in[27];
  const float* b_gate_reg    = (const float*)d_in[28];
  const float* w_gate_cat    = (const float*)d_in[29];
  const float* b_gate_cat    = (const float*)d_in[30];
  const float* col_Wp = (const float*)d_in[31];
  const float* col_We = (const float*)d_in[32];
  const float* col_Wf = (const float*)d_in[33];
  const float* reg_Wp = (const float*)d_in[34];
  const float* reg_We = (const float*)d_in[35];
  const float* reg_Wf = (const float*)d_in[36];
  const float* cat_Wp = (const float*)d_in[37];
  const float* cat_We = (const float*)d_in[38];
  const float* cat_Wf = (const float*)d_in[39];

  float* ws = (float*)d_ws;
  size_t off = 0;
  auto alloc = [&](size_t n) { float* p = ws + off; off += n; return p; };
  const size_t PD = (size_t)Pn * D;
  const size_t UD = (size_t)Un * D;
  const size_t ED = (size_t)ETn * D;

  float* colP   = alloc(PD);
  float* regP   = alloc(PD);
  float* catP   = alloc(PD);
  float* transP = alloc(PD);
  float* colU   = alloc(UD);
  float* p_buf  = alloc(PD);
  float* e_buf  = alloc(UD);
  float* tmpE1  = alloc(UD);              // hetero pe-spmm out (f32, <=Un rows)
  float* acce   = alloc((size_t)Rn * D);
  float* WeWf   = alloc(D * D);
  unsigned short* tmpP16   = (unsigned short*)alloc(PD / 2);  // bf16 gather src
  unsigned short* tmpE2_16 = (unsigned short*)alloc(UD / 2);
  unsigned short* tmpE1_16 = (unsigned short*)alloc(ED / 2);  // trans hop1 out
  unsigned short* p16      = (unsigned short*)alloc(PD / 2);  // trans p mirror
  int2*  sd     = (int2*)alloc(4 * (size_t)NNZ_T);  // both dirs, 2*nnz int2
  int*   rowptr = (int*)alloc(Pn + ETn + 2);
  int*   bktcnt = (int*)alloc(4096);
  int*   bktptr = (int*)alloc(4096);
  int*   cursorB= (int*)alloc(4096);

  const int GCAP = 1024;
  const int NB2 = cdiv(Pn, 128);  // 782 poi buckets (shift 7)

  // Build exact CSR (both directions) for one graph:
  // bucket-hist (LDS) -> 1-block scan -> binned scatter -> refine (writes
  // exact rowptr + reorders in place).
  auto sort2 = [&](const int* k1, const int* o1, const float* v1, int s1,
                   int nk1, const int* k2, const int* o2, const float* v2,
                   int nnz) {
    int nb1 = cdiv(nk1, 1 << s1);
    int nkb = nb1 + NB2;                 // bucket count (<= ~1800)
    int tot = 2 * nnz;
    hipMemsetAsync(bktcnt, 0, (size_t)nkb * sizeof(int), stream);
    int nblk = cdiv(nnz, TILE);
    hist_binned_kernel<<<nblk, 256, nkb * 4, stream>>>(k1, k2, bktcnt, s1, nb1,
                                                       nkb, nnz);
    scan_dual_kernel<<<1, 1024, 0, stream>>>(bktcnt, bktptr, cursorB, nkb);
    scatter_binned_kernel<<<nblk, 256, 2 * nkb * 4, stream>>>(
        k1, o1, v1, k2, o2, v2, cursorB, sd, s1, nb1, nkb, nnz);
    refine_kernel<<<nkb, 256, 0, stream>>>(bktptr, sd, rowptr, s1, nb1, nk1,
                                           nkb, tot);
    return nk1 + Pn;  // exact key count
  };

  auto spmm = [&](int base, int nkx, int nnz2, const unsigned short* X16,
                  float* Yf, unsigned short* Y16, float* presid, float* acc,
                  unsigned short* pm16, int nrows) {
    spmm_csr_kernel<<<cdiv(nrows, 4), 256, 0, stream>>>(
        rowptr, base, nkx, nnz2, sd, (const unsigned*)X16, Yf, (unsigned*)Y16,
        presid, acc, (unsigned*)pm16, nrows);
  };

  auto hetero = [&](const float* wg, const float* bg, const float* edge_emb,
                    int Ne, int s1, const int* poi_idx, const int* edge_idx,
                    const float* v_pe, const float* v_ep, const float* Wp,
                    const float* We, const float* Wf, int nnz, float* accP,
                    float* accE) {
    int nkx = sort2(edge_idx, poi_idx, v_pe, s1, Ne, poi_idx, edge_idx, v_ep,
                    nnz);
    gate_kernel<<<GCAP, 256, 0, stream>>>(poi_emb, wg, bg, p_buf, accP,
                                          nullptr, Pn);
    copy2_kernel<<<cdiv(Ne * D / 4, 256), 256, 0, stream>>>(
        (const float4*)edge_emb, (float4*)e_buf, (float4*)accE, Ne * D / 4);
    matmul_kernel<<<16, 256, 0, stream>>>(We, Wf + D * D, WeWf, D);  // We@Wf_bot
    for (int l = 0; l < 2; ++l) {
      matmul_bf16_kernel<<<GCAP, 256, 0, stream>>>(p_buf, Wp, tmpP16, Pn);
      spmm(0, nkx, 2 * nnz, tmpP16, tmpE1, nullptr, nullptr, nullptr, nullptr,
           Ne);  // poi_msg (dest=edge rows)
      fused2_resid_kernel<<<min(cdiv(Ne, 4), GCAP), 256, 0, stream>>>(
          tmpE1, Wf, WeWf, tmpE2_16, e_buf, accE, Ne);
      spmm(Ne, nkx, 2 * nnz, tmpE2_16, nullptr, nullptr, p_buf, accP, nullptr,
           Pn);  // prop + fused residual
    }
  };

  // --- three hetero nets (acc scaled by 1/3 in final kernel) ---
  hetero(w_gate_col, b_gate_col, user_emb, Un, 5, col_poi_idx, col_user_idx,
         col_vals_pe, col_vals_ep, col_Wp, col_We, col_Wf, NNZ_COL, colP, colU);
  hetero(w_gate_reg, b_gate_reg, region_emb, Rn, 0, reg_poi_idx,
         reg_region_idx, reg_vals_pe, reg_vals_ep, reg_Wp, reg_We, reg_Wf,
         NNZ_REG, regP, acce);
  hetero(w_gate_cat, b_gate_cat, cat_emb, Cn, 0, cat_poi_idx, cat_cat_idx,
         cat_vals_pe, cat_vals_ep, cat_Wp, cat_We, cat_Wf, NNZ_CAT, catP, acce);

  // --- directed trans net (bf16 mirror p16 is the gather source) ---
  int nkx = sort2(trans_edge_idx, trans_poi_idx, trans_vals_tar, 6, ETn,
                  trans_poi_idx, trans_edge_idx, trans_vals_src, NNZ_T);
  gate_kernel<<<GCAP, 256, 0, stream>>>(poi_emb, w_gate_trans, b_gate_trans,
                                        p_buf, transP, p16, Pn);
  for (int l = 0; l < 2; ++l) {
    spmm(0, nkx, 2 * NNZ_T, p16, nullptr, tmpE1_16, nullptr, nullptr, nullptr,
         ETn);  // msg_tar -> bf16
    spmm(ETn, nkx, 2 * NNZ_T, tmpE1_16, nullptr, nullptr, p_buf, transP, p16,
         Pn);   // msg_src + residual + mirror update
  }

  // --- sequence pooling + output ---
  final_kernel<<<cdiv(Bn * 64, 256), 256, 0, stream>>>(
      user_idx, user_seq, user_seq_mask, colP, transP, regP, catP, colU,
      (float*)d_out);
}

// Round 10
// 1154.895 us; speedup vs baseline: 1.3008x; 1.1536x over previous
//
#include <hip/hip_runtime.h>

// Problem constants (match reference setup_inputs)
#define D 64
constexpr int Pn  = 100000;
constexpr int Un  = 20000;
constexpr int Rn  = 1000;
constexpr int Cn  = 500;
constexpr int Tn  = 50;
constexpr int Bn  = 4096;
constexpr int ETn = 50000;
constexpr int NNZ_COL = 1000000;
constexpr int NNZ_REG = 300000;
constexpr int NNZ_CAT = 300000;
constexpr int NNZ_T   = 1000000;
constexpr int TILE = 8192;   // elements per scatter/hist block

static inline int cdiv(int a, int b) { return (a + b - 1) / b; }

__device__ __forceinline__ unsigned short f2bf(float f) {
  unsigned u = __float_as_uint(f);
  unsigned r = (u + 0x7FFF + ((u >> 16) & 1)) >> 16;  // round-to-nearest-even
  return (unsigned short)r;
}
__device__ __forceinline__ float bf2f(unsigned short h) {
  return __uint_as_float((unsigned)h << 16);
}
__device__ __forceinline__ float bflo(unsigned d) {
  return __uint_as_float(d << 16);
}
__device__ __forceinline__ float bfhi(unsigned d) {
  return __uint_as_float(d & 0xFFFF0000u);
}

// ---------------------------------------------------------------------------
// gate: out = x * sigmoid(x @ W + b); writes f32 Pout + f32 Aout (+ optional
// bf16 mirror of Pout for gather consumers).
// ---------------------------------------------------------------------------
__global__ __launch_bounds__(256) void gate_kernel(
    const float* __restrict__ Xin, const float* __restrict__ W,
    const float* __restrict__ bias, float* __restrict__ Pout,
    float* __restrict__ Aout, unsigned short* __restrict__ P16, int N) {
  __shared__ float sx[4][D];
  int tid = threadIdx.x, wv = tid >> 6, lane = tid & 63;
  float wcol[D];
#pragma unroll
  for (int k = 0; k < D; ++k) wcol[k] = W[k * D + lane];
  float bl = bias[lane];
  for (int row = blockIdx.x * 4 + wv; row < N; row += gridDim.x * 4) {
    float x = Xin[row * D + lane];
    sx[wv][lane] = x;
    float y = 0.f;
#pragma unroll
    for (int k = 0; k < D; ++k) y += sx[wv][k] * wcol[k];
    float s = 1.f / (1.f + __expf(-(y + bl)));
    float o = x * s;
    Pout[row * D + lane] = o;
    Aout[row * D + lane] = o;
    if (P16) P16[row * D + lane] = f2bf(o);
  }
}

// Y(f32) = X @ W  (tiny, for We@Wf_bot)
__global__ __launch_bounds__(256) void matmul_kernel(
    const float* __restrict__ Xin, const float* __restrict__ W,
    float* __restrict__ Y, int N) {
  __shared__ float sx[4][D];
  int tid = threadIdx.x, wv = tid >> 6, lane = tid & 63;
  float wcol[D];
#pragma unroll
  for (int k = 0; k < D; ++k) wcol[k] = W[k * D + lane];
  for (int row = blockIdx.x * 4 + wv; row < N; row += gridDim.x * 4) {
    sx[wv][lane] = Xin[row * D + lane];
    float y = 0.f;
#pragma unroll
    for (int k = 0; k < D; ++k) y += sx[wv][k] * wcol[k];
    Y[row * D + lane] = y;
  }
}

// Y(bf16) = X @ W  (gather-source tables)
__global__ __launch_bounds__(256) void matmul_bf16_kernel(
    const float* __restrict__ Xin, const float* __restrict__ W,
    unsigned short* __restrict__ Y, int N) {
  __shared__ float sx[4][D];
  int tid = threadIdx.x, wv = tid >> 6, lane = tid & 63;
  float wcol[D];
#pragma unroll
  for (int k = 0; k < D; ++k) wcol[k] = W[k * D + lane];
  for (int row = blockIdx.x * 4 + wv; row < N; row += gridDim.x * 4) {
    sx[wv][lane] = Xin[row * D + lane];
    float y = 0.f;
#pragma unroll
    for (int k = 0; k < D; ++k) y += sx[wv][k] * wcol[k];
    Y[row * D + lane] = f2bf(y);
  }
}

// fused hetero edge update + residual:
// fused = A@W1 + e_buf@W2 ; fusedOut16 = bf16(fused);
// e_buf += fused ; accE += e_buf(new)
__global__ __launch_bounds__(256) void fused2_resid_kernel(
    const float* __restrict__ A, const float* __restrict__ W1,
    const float* __restrict__ W2, unsigned short* __restrict__ fusedOut16,
    float* __restrict__ e_buf, float* __restrict__ accE, int N) {
  __shared__ float sa[4][D], sb2[4][D];
  int tid = threadIdx.x, wv = tid >> 6, lane = tid & 63;
  float w1[D], w2[D];
#pragma unroll
  for (int k = 0; k < D; ++k) {
    w1[k] = W1[k * D + lane];
    w2[k] = W2[k * D + lane];
  }
  for (int row = blockIdx.x * 4 + wv; row < N; row += gridDim.x * 4) {
    sa[wv][lane]  = A[row * D + lane];
    float eo = e_buf[row * D + lane];
    sb2[wv][lane] = eo;
    float y = 0.f;
#pragma unroll
    for (int k = 0; k < D; ++k) y += sa[wv][k] * w1[k] + sb2[wv][k] * w2[k];
    fusedOut16[row * D + lane] = f2bf(y);
    float en = eo + y;
    e_buf[row * D + lane] = en;
    accE[row * D + lane] += en;
  }
}

// ---------------------------------------------------------------------------
// LDS-privatized bucket histogram (1024 threads for latency hiding).
// ---------------------------------------------------------------------------
__global__ __launch_bounds__(1024) void hist_binned_kernel(
    const int* __restrict__ k1, const int* __restrict__ k2,
    int* __restrict__ counts, int s1, int nb1, int nk, int nnz) {
  extern __shared__ int lh[];
  int tid = threadIdx.x;
  for (int k = tid; k < nk; k += 1024) lh[k] = 0;
  __syncthreads();
  int t0 = blockIdx.x * TILE, t1 = min(t0 + TILE, nnz);
  for (int i = t0 + tid; i < t1; i += 1024) {
    atomicAdd(&lh[k1[i] >> s1], 1);
    atomicAdd(&lh[nb1 + (k2[i] >> 7)], 1);
  }
  __syncthreads();
  for (int k = tid; k < nk; k += 1024) {
    int c = lh[k];
    if (c) atomicAdd(&counts[k], c);
  }
}

// single-block exclusive scan over n <= 4096 bucket counts; dual output
// (bktptr stays pristine for refine; cursorB is mutated by scatter).
__global__ __launch_bounds__(1024) void scan_dual_kernel(
    const int* __restrict__ in, int* __restrict__ bktptr,
    int* __restrict__ cursorB, int n) {
  __shared__ int lds[16];
  int tid = threadIdx.x, lane = tid & 63, wv = tid >> 6;
  int x[4];
  int s = 0;
#pragma unroll
  for (int e = 0; e < 4; ++e) {
    int i = tid * 4 + e;
    x[e] = (i < n) ? in[i] : 0;
    s += x[e];
  }
  int sc = s;
#pragma unroll
  for (int d = 1; d < 64; d <<= 1) {
    int y = __shfl_up(sc, d);
    if (lane >= d) sc += y;
  }
  if (lane == 63) lds[wv] = sc;
  __syncthreads();
  if (tid < 16) {
    int w = lds[tid];
#pragma unroll
    for (int d = 1; d < 16; d <<= 1) {
      int y = __shfl_up(w, d);
      if (lane >= d) w += y;
    }
    lds[tid] = w;
  }
  __syncthreads();
  int woff = (wv == 0) ? 0 : lds[wv - 1];
  int excl = woff + sc - s;
#pragma unroll
  for (int e = 0; e < 4; ++e) {
    int i = tid * 4 + e;
    if (i < n) {
      bktptr[i] = excl;
      cursorB[i] = excl;
    }
    excl += x[e];
  }
}

// LDS-binned scatter into bucket-grouped layout (line-friendly runs).
// 1024 threads for latency hiding. Payload .x = (row_local << 17) | other.
__global__ __launch_bounds__(1024) void scatter_binned_kernel(
    const int* __restrict__ k1, const int* __restrict__ o1,
    const float* __restrict__ v1, const int* __restrict__ k2,
    const int* __restrict__ o2, const float* __restrict__ v2,
    int* __restrict__ cursorB, int2* __restrict__ sd, int s1, int nb1, int nk,
    int nnz) {
  extern __shared__ int ls[];  // [0,nk)=cnt, [nk,2nk)=base
  int* cnt = ls;
  int* bas = ls + nk;
  int tid = threadIdx.x;
  for (int k = tid; k < nk; k += 1024) cnt[k] = 0;
  __syncthreads();
  int t0 = blockIdx.x * TILE, t1 = min(t0 + TILE, nnz);
  for (int i = t0 + tid; i < t1; i += 1024) {
    atomicAdd(&cnt[k1[i] >> s1], 1);
    atomicAdd(&cnt[nb1 + (k2[i] >> 7)], 1);
  }
  __syncthreads();
  for (int k = tid; k < nk; k += 1024) {
    int c = cnt[k];
    bas[k] = c ? atomicAdd(&cursorB[k], c) : 0;
  }
  __syncthreads();
  for (int k = tid; k < nk; k += 1024) cnt[k] = 0;
  __syncthreads();
  int m1 = (1 << s1) - 1;
  for (int i = t0 + tid; i < t1; i += 1024) {
    int r1 = k1[i], key1 = r1 >> s1;
    int off1 = atomicAdd(&cnt[key1], 1);
    sd[bas[key1] + off1] =
        make_int2(((r1 & m1) << 17) | o1[i], __float_as_int(v1[i]));
    int r2 = k2[i], key2 = nb1 + (r2 >> 7);
    int off2 = atomicAdd(&cnt[key2], 1);
    sd[bas[key2] + off2] =
        make_int2(((r2 & 127) << 17) | o2[i], __float_as_int(v2[i]));
  }
}

// ---------------------------------------------------------------------------
// Refine: bucket-grouped -> exact row-grouped IN PLACE, and WRITE exact
// rowptr (bucket_start + within-bucket exclusive row offsets). Block per
// bucket; <=4096 elems staged in registers (static idx). rows==1 buckets
// (exact already): just write rowptr, skip reorder.
// ---------------------------------------------------------------------------
__global__ __launch_bounds__(256) void refine_kernel(
    const int* __restrict__ bktptr, int2* __restrict__ sd,
    int* __restrict__ rowptr, int s1, int nb1, int nk1, int nkb, int tot) {
  __shared__ int cnt[128];
  __shared__ int wsum[2];
  int tid = threadIdx.x, b = blockIdx.x;
  int sft, row0, kbase, klim;
  if (b < nb1) {
    sft = s1; row0 = b << s1; kbase = 0; klim = nk1;
  } else {
    sft = 7; row0 = (b - nb1) << 7; kbase = nk1; klim = Pn;
  }
  int rows = min(1 << sft, klim - row0);
  int bstart = bktptr[b];
  int bend = (b + 1 < nkb) ? bktptr[b + 1] : tot;
  if (rows == 1) {
    if (tid == 0) rowptr[kbase + row0] = bstart;
    return;
  }
  if (tid < rows) cnt[tid] = 0;
  __syncthreads();
  int2 st[16];
#pragma unroll
  for (int j = 0; j < 16; ++j) {
    int i = bstart + tid + (j << 8);
    st[j] = (i < bend) ? sd[i] : make_int2(0, 0);
  }
#pragma unroll
  for (int j = 0; j < 16; ++j) {
    int i = bstart + tid + (j << 8);
    if (i < bend) atomicAdd(&cnt[st[j].x >> 17], 1);
  }
  __syncthreads();
  // exclusive scan of cnt[0..rows) by threads 0..127 (2 waves)
  int v = 0, sc = 0;
  if (tid < 128) {
    v = (tid < rows) ? cnt[tid] : 0;
    sc = v;
    int lane = tid & 63;
#pragma unroll
    for (int d = 1; d < 64; d <<= 1) {
      int y = __shfl_up(sc, d);
      if (lane >= d) sc += y;
    }
    if (lane == 63) wsum[tid >> 6] = sc;
  }
  __syncthreads();
  int excl = sc - v + ((tid >= 64 && tid < 128) ? wsum[0] : 0);
  __syncthreads();  // cnt reads done before overwrite
  if (tid < rows) {
    rowptr[kbase + row0 + tid] = bstart + excl;
    cnt[tid] = excl;  // becomes placement cursor
  }
  __syncthreads();
#pragma unroll
  for (int j = 0; j < 16; ++j) {
    int i = bstart + tid + (j << 8);
    if (i < bend) {
      int r = st[j].x >> 17;
      int dst = bstart + atomicAdd(&cnt[r], 1);
      sd[dst] = st[j];
    }
  }
}

// ---------------------------------------------------------------------------
// Exact-CSR SpMM, wave per row, 4 nnz per gather instruction: quarter q
// (16 lanes x uint2 = 128B bf16 row) handles nnz n+q. Merge via shfl ^16,^32;
// lanes 0-15 do float4 epilogue.
// ---------------------------------------------------------------------------
__global__ __launch_bounds__(256) void spmm_csr_kernel(
    const int* __restrict__ rowptr, int base, int nkx, int tot,
    const int2* __restrict__ sd, const uint2* __restrict__ X64,
    float* __restrict__ Yf, uint2* __restrict__ Y64,
    float* __restrict__ presid, float* __restrict__ acc,
    uint2* __restrict__ pm64, int nrows) {
  int lane = threadIdx.x & 63;
  int q = lane >> 4, l4 = lane & 15;
  int w = (int)((blockIdx.x * (long)blockDim.x + threadIdx.x) >> 6);
  if (w >= nrows) return;
  int idx = base + w;
  int start = rowptr[idx];
  int end = (idx + 1 == nkx) ? tot : rowptr[idx + 1];
  float a0 = 0.f, a1 = 0.f, a2 = 0.f, a3 = 0.f;
  float b0 = 0.f, b1 = 0.f, b2 = 0.f, b3 = 0.f;
  int n = start + q;  // this quarter's nnz stream (stride 4)
  for (; n + 4 < end; n += 8) {
    int2 c0 = sd[n], c1 = sd[n + 4];
    uint2 d0 = X64[(size_t)(c0.x & 0x1FFFF) * 16 + l4];
    uint2 d1 = X64[(size_t)(c1.x & 0x1FFFF) * 16 + l4];
    float v0 = __int_as_float(c0.y), v1 = __int_as_float(c1.y);
    a0 += v0 * bflo(d0.x); a1 += v0 * bfhi(d0.x);
    a2 += v0 * bflo(d0.y); a3 += v0 * bfhi(d0.y);
    b0 += v1 * bflo(d1.x); b1 += v1 * bfhi(d1.x);
    b2 += v1 * bflo(d1.y); b3 += v1 * bfhi(d1.y);
  }
  for (; n < end; n += 4) {
    int2 cv = sd[n];
    uint2 dv = X64[(size_t)(cv.x & 0x1FFFF) * 16 + l4];
    float vv = __int_as_float(cv.y);
    a0 += vv * bflo(dv.x); a1 += vv * bfhi(dv.x);
    a2 += vv * bflo(dv.y); a3 += vv * bfhi(dv.y);
  }
  float y0 = a0 + b0, y1 = a1 + b1, y2 = a2 + b2, y3 = a3 + b3;
  y0 += __shfl(y0, lane ^ 16); y1 += __shfl(y1, lane ^ 16);
  y2 += __shfl(y2, lane ^ 16); y3 += __shfl(y3, lane ^ 16);
  y0 += __shfl(y0, lane ^ 32); y1 += __shfl(y1, lane ^ 32);
  y2 += __shfl(y2, lane ^ 32); y3 += __shfl(y3, lane ^ 32);
  if (lane >= 16) return;
  // lane l4 holds row elements 4*l4 .. 4*l4+3
  size_t o = (size_t)w * D + 4 * l4;
  if (presid) {
    float4 p = *(float4*)&presid[o];
    p.x += y0; p.y += y1; p.z += y2; p.w += y3;
    *(float4*)&presid[o] = p;
    float4 av = *(float4*)&acc[o];
    av.x += p.x; av.y += p.y; av.z += p.z; av.w += p.w;
    *(float4*)&acc[o] = av;
    if (pm64) {
      uint2 pk;
      pk.x = (unsigned)f2bf(p.x) | ((unsigned)f2bf(p.y) << 16);
      pk.y = (unsigned)f2bf(p.z) | ((unsigned)f2bf(p.w) << 16);
      pm64[(size_t)w * 16 + l4] = pk;
    }
  } else if (Y64) {
    uint2 pk;
    pk.x = (unsigned)f2bf(y0) | ((unsigned)f2bf(y1) << 16);
    pk.y = (unsigned)f2bf(y2) | ((unsigned)f2bf(y3) << 16);
    Y64[(size_t)w * 16 + l4] = pk;
  } else {
    float4 yv; yv.x = y0; yv.y = y1; yv.z = y2; yv.w = y3;
    *(float4*)&Yf[o] = yv;
  }
}

// a = src; b = src  (float4)
__global__ __launch_bounds__(256) void copy2_kernel(
    const float4* __restrict__ s, float4* __restrict__ a,
    float4* __restrict__ b, int n4) {
  int i = blockIdx.x * blockDim.x + threadIdx.x;
  if (i < n4) {
    float4 v = s[i];
    a[i] = v;
    b[i] = v;
  }
}

// Final pooling: masked mean over T of 4 padded tables + user add, scale 1/3.
__global__ __launch_bounds__(256) void final_kernel(
    const int* __restrict__ user_idx, const int* __restrict__ seq,
    const int* __restrict__ mask, const float* __restrict__ colP,
    const float* __restrict__ transP, const float* __restrict__ regP,
    const float* __restrict__ catP, const float* __restrict__ colU,
    float* __restrict__ out) {
  int wid = (int)((blockIdx.x * blockDim.x + threadIdx.x) >> 6);
  int lane = threadIdx.x & 63;
  if (wid >= Bn) return;
  float sc = 0.f, st = 0.f, sr = 0.f, sca = 0.f;
  int cnt = 0;
  for (int t = 0; t < Tn; ++t) {
    int m = mask[wid * Tn + t];
    int idx = seq[wid * Tn + t];
    cnt += m;
    if (m && idx < Pn) {
      sc  += colP[idx * D + lane];
      st  += transP[idx * D + lane];
      sr  += regP[idx * D + lane];
      sca += catP[idx * D + lane];
    }
  }
  float dn = 1.f / (float)(cnt > 0 ? cnt : 1);
  const float inv = 1.f / 3.f;  // 1/(N_LAYERS+1), common to all four nets
  int u = user_idx[wid];
  out[0 * Bn * D + wid * D + lane] = (colU[u * D + lane] + sc * dn) * inv;
  out[1 * Bn * D + wid * D + lane] = st * dn * inv;
  out[2 * Bn * D + wid * D + lane] = sr * dn * inv;
  out[3 * Bn * D + wid * D + lane] = sca * dn * inv;
}

extern "C" void kernel_launch(void* const* d_in, const int* in_sizes, int n_in,
                              void* d_out, int out_size, void* d_ws,
                              size_t ws_size, hipStream_t stream) {
  (void)in_sizes; (void)n_in; (void)out_size; (void)ws_size;
  const int*   user_idx      = (const int*)d_in[0];
  const int*   user_seq      = (const int*)d_in[1];
  const int*   user_seq_mask = (const int*)d_in[2];
  const int*   col_poi_idx   = (const int*)d_in[3];
  const int*   col_user_idx  = (const int*)d_in[4];
  const float* col_vals_pe   = (const float*)d_in[5];
  const float* col_vals_ep   = (const float*)d_in[6];
  const int*   reg_poi_idx   = (const int*)d_in[7];
  const int*   reg_region_idx= (const int*)d_in[8];
  const float* reg_vals_pe   = (const float*)d_in[9];
  const float* reg_vals_ep   = (const float*)d_in[10];
  const int*   cat_poi_idx   = (const int*)d_in[11];
  const int*   cat_cat_idx   = (const int*)d_in[12];
  const float* cat_vals_pe   = (const float*)d_in[13];
  const float* cat_vals_ep   = (const float*)d_in[14];
  const int*   trans_poi_idx = (const int*)d_in[15];
  const int*   trans_edge_idx= (const int*)d_in[16];
  const float* trans_vals_tar= (const float*)d_in[17];
  const float* trans_vals_src= (const float*)d_in[18];
  const float* poi_emb       = (const float*)d_in[19];
  const float* user_emb      = (const float*)d_in[20];
  const float* region_emb    = (const float*)d_in[21];
  const float* cat_emb       = (const float*)d_in[22];
  const float* w_gate_col    = (const float*)d_in[23];
  const float* b_gate_col    = (const float*)d_in[24];
  const float* w_gate_trans  = (const float*)d_in[25];
  const float* b_gate_trans  = (const float*)d_in[26];
  const float* w_gate_reg    = (const float*)d_in[27];
  const float* b_gate_reg    = (const float*)d_in[28];
  const float* w_gate_cat    = (const float*)d_in[29];
  const float* b_gate_cat    = (const float*)d_in[30];
  const float* col_Wp = (const float*)d_in[31];
  const float* col_We = (const float*)d_in[32];
  const float* col_Wf = (const float*)d_in[33];
  const float* reg_Wp = (const float*)d_in[34];
  const float* reg_We = (const float*)d_in[35];
  const float* reg_Wf = (const float*)d_in[36];
  const float* cat_Wp = (const float*)d_in[37];
  const float* cat_We = (const float*)d_in[38];
  const float* cat_Wf = (const float*)d_in[39];

  float* ws = (float*)d_ws;
  size_t off = 0;
  auto alloc = [&](size_t n) { float* p = ws + off; off += n; return p; };
  const size_t PD = (size_t)Pn * D;
  const size_t UD = (size_t)Un * D;
  const size_t ED = (size_t)ETn * D;

  float* colP   = alloc(PD);
  float* regP   = alloc(PD);
  float* catP   = alloc(PD);
  float* transP = alloc(PD);
  float* colU   = alloc(UD);
  float* p_buf  = alloc(PD);
  float* e_buf  = alloc(UD);
  float* tmpE1  = alloc(UD);              // hetero pe-spmm out (f32, <=Un rows)
  float* acce   = alloc((size_t)Rn * D);
  float* WeWf   = alloc(D * D);
  unsigned short* tmpP16   = (unsigned short*)alloc(PD / 2);  // bf16 gather src
  unsigned short* tmpE2_16 = (unsigned short*)alloc(UD / 2);
  unsigned short* tmpE1_16 = (unsigned short*)alloc(ED / 2);  // trans hop1 out
  unsigned short* p16      = (unsigned short*)alloc(PD / 2);  // trans p mirror
  int2*  sd     = (int2*)alloc(4 * (size_t)NNZ_T);  // both dirs, 2*nnz int2
  int*   rowptr = (int*)alloc(Pn + ETn + 2);
  int*   bktcnt = (int*)alloc(4096);
  int*   bktptr = (int*)alloc(4096);
  int*   cursorB= (int*)alloc(4096);

  const int GCAP = 1024;
  const int NB2 = cdiv(Pn, 128);  // 782 poi buckets (shift 7)

  // Build exact CSR (both directions) for one graph:
  // bucket-hist (LDS) -> 1-block scan -> binned scatter -> refine (writes
  // exact rowptr + reorders in place).
  auto sort2 = [&](const int* k1, const int* o1, const float* v1, int s1,
                   int nk1, const int* k2, const int* o2, const float* v2,
                   int nnz) {
    int nb1 = cdiv(nk1, 1 << s1);
    int nkb = nb1 + NB2;                 // bucket count (<= ~1800)
    int tot = 2 * nnz;
    hipMemsetAsync(bktcnt, 0, (size_t)nkb * sizeof(int), stream);
    int nblk = cdiv(nnz, TILE);
    hist_binned_kernel<<<nblk, 1024, nkb * 4, stream>>>(k1, k2, bktcnt, s1,
                                                        nb1, nkb, nnz);
    scan_dual_kernel<<<1, 1024, 0, stream>>>(bktcnt, bktptr, cursorB, nkb);
    scatter_binned_kernel<<<nblk, 1024, 2 * nkb * 4, stream>>>(
        k1, o1, v1, k2, o2, v2, cursorB, sd, s1, nb1, nkb, nnz);
    refine_kernel<<<nkb, 256, 0, stream>>>(bktptr, sd, rowptr, s1, nb1, nk1,
                                           nkb, tot);
    return nk1 + Pn;  // exact key count
  };

  auto spmm = [&](int base, int nkx, int nnz2, const unsigned short* X16,
                  float* Yf, unsigned short* Y16, float* presid, float* acc,
                  unsigned short* pm16, int nrows) {
    spmm_csr_kernel<<<cdiv(nrows, 4), 256, 0, stream>>>(
        rowptr, base, nkx, nnz2, sd, (const uint2*)X16, Yf, (uint2*)Y16,
        presid, acc, (uint2*)pm16, nrows);
  };

  auto hetero = [&](const float* wg, const float* bg, const float* edge_emb,
                    int Ne, int s1, const int* poi_idx, const int* edge_idx,
                    const float* v_pe, const float* v_ep, const float* Wp,
                    const float* We, const float* Wf, int nnz, float* accP,
                    float* accE) {
    int nkx = sort2(edge_idx, poi_idx, v_pe, s1, Ne, poi_idx, edge_idx, v_ep,
                    nnz);
    gate_kernel<<<GCAP, 256, 0, stream>>>(poi_emb, wg, bg, p_buf, accP,
                                          nullptr, Pn);
    copy2_kernel<<<cdiv(Ne * D / 4, 256), 256, 0, stream>>>(
        (const float4*)edge_emb, (float4*)e_buf, (float4*)accE, Ne * D / 4);
    matmul_kernel<<<16, 256, 0, stream>>>(We, Wf + D * D, WeWf, D);  // We@Wf_bot
    for (int l = 0; l < 2; ++l) {
      matmul_bf16_kernel<<<GCAP, 256, 0, stream>>>(p_buf, Wp, tmpP16, Pn);
      spmm(0, nkx, 2 * nnz, tmpP16, tmpE1, nullptr, nullptr, nullptr, nullptr,
           Ne);  // poi_msg (dest=edge rows)
      fused2_resid_kernel<<<min(cdiv(Ne, 4), GCAP), 256, 0, stream>>>(
          tmpE1, Wf, WeWf, tmpE2_16, e_buf, accE, Ne);
      spmm(Ne, nkx, 2 * nnz, tmpE2_16, nullptr, nullptr, p_buf, accP, nullptr,
           Pn);  // prop + fused residual
    }
  };

  // --- three hetero nets (acc scaled by 1/3 in final kernel) ---
  hetero(w_gate_col, b_gate_col, user_emb, Un, 5, col_poi_idx, col_user_idx,
         col_vals_pe, col_vals_ep, col_Wp, col_We, col_Wf, NNZ_COL, colP, colU);
  hetero(w_gate_reg, b_gate_reg, region_emb, Rn, 0, reg_poi_idx,
         reg_region_idx, reg_vals_pe, reg_vals_ep, reg_Wp, reg_We, reg_Wf,
         NNZ_REG, regP, acce);
  hetero(w_gate_cat, b_gate_cat, cat_emb, Cn, 0, cat_poi_idx, cat_cat_idx,
         cat_vals_pe, cat_vals_ep, cat_Wp, cat_We, cat_Wf, NNZ_CAT, catP, acce);

  // --- directed trans net (bf16 mirror p16 is the gather source) ---
  int nkx = sort2(trans_edge_idx, trans_poi_idx, trans_vals_tar, 6, ETn,
                  trans_poi_idx, trans_edge_idx, trans_vals_src, NNZ_T);
  gate_kernel<<<GCAP, 256, 0, stream>>>(poi_emb, w_gate_trans, b_gate_trans,
                                        p_buf, transP, p16, Pn);
  for (int l = 0; l < 2; ++l) {
    spmm(0, nkx, 2 * NNZ_T, p16, nullptr, tmpE1_16, nullptr, nullptr, nullptr,
         ETn);  // msg_tar -> bf16
    spmm(ETn, nkx, 2 * NNZ_T, tmpE1_16, nullptr, nullptr, p_buf, transP, p16,
         Pn);   // msg_src + residual + mirror update
  }

  // --- sequence pooling + output ---
  final_kernel<<<cdiv(Bn * 64, 256), 256, 0, stream>>>(
      user_idx, user_seq, user_seq_mask, colP, transP, regP, catP, colU,
      (float*)d_out);
}

// Round 11
// 1099.060 us; speedup vs baseline: 1.3669x; 1.0508x over previous
//
#include <hip/hip_runtime.h>

// Problem constants (match reference setup_inputs)
#define D 64
constexpr int Pn  = 100000;
constexpr int Un  = 20000;
constexpr int Rn  = 1000;
constexpr int Cn  = 500;
constexpr int Tn  = 50;
constexpr int Bn  = 4096;
constexpr int ETn = 50000;
constexpr int NNZ_COL = 1000000;
constexpr int NNZ_REG = 300000;
constexpr int NNZ_CAT = 300000;
constexpr int NNZ_T   = 1000000;
constexpr int TILE = 8192;   // elements per scatter/hist block (per direction)

static inline int cdiv(int a, int b) { return (a + b - 1) / b; }

__device__ __forceinline__ unsigned short f2bf(float f) {
  unsigned u = __float_as_uint(f);
  unsigned r = (u + 0x7FFF + ((u >> 16) & 1)) >> 16;  // round-to-nearest-even
  return (unsigned short)r;
}
__device__ __forceinline__ float bflo(unsigned d) {
  return __uint_as_float(d << 16);
}
__device__ __forceinline__ float bfhi(unsigned d) {
  return __uint_as_float(d & 0xFFFF0000u);
}

// ---------------------------------------------------------------------------
// gate: out = x * sigmoid(x @ W + b); writes f32 Pout + f32 Aout (+ optional
// bf16 mirror of Pout for gather consumers).
// ---------------------------------------------------------------------------
__global__ __launch_bounds__(256) void gate_kernel(
    const float* __restrict__ Xin, const float* __restrict__ W,
    const float* __restrict__ bias, float* __restrict__ Pout,
    float* __restrict__ Aout, unsigned short* __restrict__ P16, int N) {
  __shared__ float sx[4][D];
  int tid = threadIdx.x, wv = tid >> 6, lane = tid & 63;
  float wcol[D];
#pragma unroll
  for (int k = 0; k < D; ++k) wcol[k] = W[k * D + lane];
  float bl = bias[lane];
  for (int row = blockIdx.x * 4 + wv; row < N; row += gridDim.x * 4) {
    float x = Xin[row * D + lane];
    sx[wv][lane] = x;
    float y = 0.f;
#pragma unroll
    for (int k = 0; k < D; ++k) y += sx[wv][k] * wcol[k];
    float s = 1.f / (1.f + __expf(-(y + bl)));
    float o = x * s;
    Pout[row * D + lane] = o;
    Aout[row * D + lane] = o;
    if (P16) P16[row * D + lane] = f2bf(o);
  }
}

// Y(f32) = X @ W  (tiny, for We@Wf_bot)
__global__ __launch_bounds__(256) void matmul_kernel(
    const float* __restrict__ Xin, const float* __restrict__ W,
    float* __restrict__ Y, int N) {
  __shared__ float sx[4][D];
  int tid = threadIdx.x, wv = tid >> 6, lane = tid & 63;
  float wcol[D];
#pragma unroll
  for (int k = 0; k < D; ++k) wcol[k] = W[k * D + lane];
  for (int row = blockIdx.x * 4 + wv; row < N; row += gridDim.x * 4) {
    sx[wv][lane] = Xin[row * D + lane];
    float y = 0.f;
#pragma unroll
    for (int k = 0; k < D; ++k) y += sx[wv][k] * wcol[k];
    Y[row * D + lane] = y;
  }
}

// Y(bf16) = X @ W  (gather-source tables)
__global__ __launch_bounds__(256) void matmul_bf16_kernel(
    const float* __restrict__ Xin, const float* __restrict__ W,
    unsigned short* __restrict__ Y, int N) {
  __shared__ float sx[4][D];
  int tid = threadIdx.x, wv = tid >> 6, lane = tid & 63;
  float wcol[D];
#pragma unroll
  for (int k = 0; k < D; ++k) wcol[k] = W[k * D + lane];
  for (int row = blockIdx.x * 4 + wv; row < N; row += gridDim.x * 4) {
    sx[wv][lane] = Xin[row * D + lane];
    float y = 0.f;
#pragma unroll
    for (int k = 0; k < D; ++k) y += sx[wv][k] * wcol[k];
    Y[row * D + lane] = f2bf(y);
  }
}

// fused hetero edge update + residual:
// fused = A@W1 + e_buf@W2 ; fusedOut16 = bf16(fused);
// e_buf += fused ; accE += e_buf(new)
__global__ __launch_bounds__(256) void fused2_resid_kernel(
    const float* __restrict__ A, const float* __restrict__ W1,
    const float* __restrict__ W2, unsigned short* __restrict__ fusedOut16,
    float* __restrict__ e_buf, float* __restrict__ accE, int N) {
  __shared__ float sa[4][D], sb2[4][D];
  int tid = threadIdx.x, wv = tid >> 6, lane = tid & 63;
  float w1[D], w2[D];
#pragma unroll
  for (int k = 0; k < D; ++k) {
    w1[k] = W1[k * D + lane];
    w2[k] = W2[k * D + lane];
  }
  for (int row = blockIdx.x * 4 + wv; row < N; row += gridDim.x * 4) {
    sa[wv][lane]  = A[row * D + lane];
    float eo = e_buf[row * D + lane];
    sb2[wv][lane] = eo;
    float y = 0.f;
#pragma unroll
    for (int k = 0; k < D; ++k) y += sa[wv][k] * w1[k] + sb2[wv][k] * w2[k];
    fusedOut16[row * D + lane] = f2bf(y);
    float en = eo + y;
    e_buf[row * D + lane] = en;
    accE[row * D + lane] += en;
  }
}

// ---------------------------------------------------------------------------
// Direction-split LDS bucket histogram: block b < nblk -> dir1 tile b;
// b >= nblk -> dir2 tile (b-nblk). 2x CU coverage vs combined.
// ---------------------------------------------------------------------------
__global__ __launch_bounds__(1024) void hist_binned_kernel(
    const int* __restrict__ k1, const int* __restrict__ k2,
    int* __restrict__ counts, int s1, int nb1, int nb2, int nblk, int nnz) {
  extern __shared__ int lh[];
  int b = blockIdx.x;
  bool d2 = b >= nblk;
  const int* kk = d2 ? k2 : k1;
  int sft = d2 ? 7 : s1;
  int kb = d2 ? nb1 : 0;
  int nb = d2 ? nb2 : nb1;
  int tile = d2 ? b - nblk : b;
  int tid = threadIdx.x;
  for (int k = tid; k < nb; k += 1024) lh[k] = 0;
  __syncthreads();
  int t0 = tile * TILE, t1 = min(t0 + TILE, nnz);
  for (int i = t0 + tid; i < t1; i += 1024) atomicAdd(&lh[kk[i] >> sft], 1);
  __syncthreads();
  for (int k = tid; k < nb; k += 1024) {
    int c = lh[k];
    if (c) atomicAdd(&counts[kb + k], c);
  }
}

// single-block exclusive scan over n <= 4096 bucket counts; dual output
// (bktptr stays pristine for refine; cursorB is mutated by scatter).
__global__ __launch_bounds__(1024) void scan_dual_kernel(
    const int* __restrict__ in, int* __restrict__ bktptr,
    int* __restrict__ cursorB, int n) {
  __shared__ int lds[16];
  int tid = threadIdx.x, lane = tid & 63, wv = tid >> 6;
  int x[4];
  int s = 0;
#pragma unroll
  for (int e = 0; e < 4; ++e) {
    int i = tid * 4 + e;
    x[e] = (i < n) ? in[i] : 0;
    s += x[e];
  }
  int sc = s;
#pragma unroll
  for (int d = 1; d < 64; d <<= 1) {
    int y = __shfl_up(sc, d);
    if (lane >= d) sc += y;
  }
  if (lane == 63) lds[wv] = sc;
  __syncthreads();
  if (tid < 16) {
    int w = lds[tid];
#pragma unroll
    for (int d = 1; d < 16; d <<= 1) {
      int y = __shfl_up(w, d);
      if (lane >= d) w += y;
    }
    lds[tid] = w;
  }
  __syncthreads();
  int woff = (wv == 0) ? 0 : lds[wv - 1];
  int excl = woff + sc - s;
#pragma unroll
  for (int e = 0; e < 4; ++e) {
    int i = tid * 4 + e;
    if (i < n) {
      bktptr[i] = excl;
      cursorB[i] = excl;
    }
    excl += x[e];
  }
}

// Direction-split LDS-binned scatter (same split as hist). Payload
// .x = (row_local << 17) | other_idx.
__global__ __launch_bounds__(1024) void scatter_binned_kernel(
    const int* __restrict__ k1, const int* __restrict__ o1,
    const float* __restrict__ v1, const int* __restrict__ k2,
    const int* __restrict__ o2, const float* __restrict__ v2,
    int* __restrict__ cursorB, int2* __restrict__ sd, int s1, int nb1, int nb2,
    int nblk, int nnz) {
  extern __shared__ int ls[];  // [0,nb)=cnt, [nb,2nb)=base
  int b = blockIdx.x;
  bool d2 = b >= nblk;
  const int* kk = d2 ? k2 : k1;
  const int* oo = d2 ? o2 : o1;
  const float* vv = d2 ? v2 : v1;
  int sft = d2 ? 7 : s1;
  int kb = d2 ? nb1 : 0;
  int nb = d2 ? nb2 : nb1;
  int msk = (1 << sft) - 1;
  int tile = d2 ? b - nblk : b;
  int* cnt = ls;
  int* bas = ls + nb;
  int tid = threadIdx.x;
  for (int k = tid; k < nb; k += 1024) cnt[k] = 0;
  __syncthreads();
  int t0 = tile * TILE, t1 = min(t0 + TILE, nnz);
  for (int i = t0 + tid; i < t1; i += 1024) atomicAdd(&cnt[kk[i] >> sft], 1);
  __syncthreads();
  for (int k = tid; k < nb; k += 1024) {
    int c = cnt[k];
    bas[k] = c ? atomicAdd(&cursorB[kb + k], c) : 0;
  }
  __syncthreads();
  for (int k = tid; k < nb; k += 1024) cnt[k] = 0;
  __syncthreads();
  for (int i = t0 + tid; i < t1; i += 1024) {
    int r = kk[i], key = r >> sft;
    int off = atomicAdd(&cnt[key], 1);
    sd[bas[key] + off] =
        make_int2(((r & msk) << 17) | oo[i], __float_as_int(vv[i]));
  }
}

// ---------------------------------------------------------------------------
// Refine: bucket-grouped -> exact row-grouped IN PLACE, and WRITE exact
// rowptr. Block per bucket; <=4096 elems staged in registers. rows==1
// buckets: just write rowptr, skip reorder.
// ---------------------------------------------------------------------------
__global__ __launch_bounds__(256) void refine_kernel(
    const int* __restrict__ bktptr, int2* __restrict__ sd,
    int* __restrict__ rowptr, int s1, int nb1, int nk1, int nkb, int tot) {
  __shared__ int cnt[128];
  __shared__ int wsum[2];
  int tid = threadIdx.x, b = blockIdx.x;
  int sft, row0, kbase, klim;
  if (b < nb1) {
    sft = s1; row0 = b << s1; kbase = 0; klim = nk1;
  } else {
    sft = 7; row0 = (b - nb1) << 7; kbase = nk1; klim = Pn;
  }
  int rows = min(1 << sft, klim - row0);
  int bstart = bktptr[b];
  int bend = (b + 1 < nkb) ? bktptr[b + 1] : tot;
  if (rows == 1) {
    if (tid == 0) rowptr[kbase + row0] = bstart;
    return;
  }
  if (tid < rows) cnt[tid] = 0;
  __syncthreads();
  int2 st[16];
#pragma unroll
  for (int j = 0; j < 16; ++j) {
    int i = bstart + tid + (j << 8);
    st[j] = (i < bend) ? sd[i] : make_int2(0, 0);
  }
#pragma unroll
  for (int j = 0; j < 16; ++j) {
    int i = bstart + tid + (j << 8);
    if (i < bend) atomicAdd(&cnt[st[j].x >> 17], 1);
  }
  __syncthreads();
  // exclusive scan of cnt[0..rows) by threads 0..127 (2 waves)
  int v = 0, sc = 0;
  if (tid < 128) {
    v = (tid < rows) ? cnt[tid] : 0;
    sc = v;
    int lane = tid & 63;
#pragma unroll
    for (int d = 1; d < 64; d <<= 1) {
      int y = __shfl_up(sc, d);
      if (lane >= d) sc += y;
    }
    if (lane == 63) wsum[tid >> 6] = sc;
  }
  __syncthreads();
  int excl = sc - v + ((tid >= 64 && tid < 128) ? wsum[0] : 0);
  __syncthreads();  // cnt reads done before overwrite
  if (tid < rows) {
    rowptr[kbase + row0 + tid] = bstart + excl;
    cnt[tid] = excl;  // becomes placement cursor
  }
  __syncthreads();
#pragma unroll
  for (int j = 0; j < 16; ++j) {
    int i = bstart + tid + (j << 8);
    if (i < bend) {
      int r = st[j].x >> 17;
      int dst = bstart + atomicAdd(&cnt[r], 1);
      sd[dst] = st[j];
    }
  }
}

// ---------------------------------------------------------------------------
// Exact-CSR SpMM, wave per row, 4 nnz per gather instruction (16 lanes x
// uint2 = 128B bf16 row per nnz). Merge via shfl ^16,^32; lanes 0-15 do
// float4 epilogue. Optional bf16 mirrors of updated presid (pm64) and
// updated acc (am64).
// ---------------------------------------------------------------------------
__global__ __launch_bounds__(256) void spmm_csr_kernel(
    const int* __restrict__ rowptr, int base, int nkx, int tot,
    const int2* __restrict__ sd, const uint2* __restrict__ X64,
    float* __restrict__ Yf, uint2* __restrict__ Y64,
    float* __restrict__ presid, float* __restrict__ acc,
    uint2* __restrict__ pm64, uint2* __restrict__ am64, int nrows) {
  int lane = threadIdx.x & 63;
  int q = lane >> 4, l4 = lane & 15;
  int w = (int)((blockIdx.x * (long)blockDim.x + threadIdx.x) >> 6);
  if (w >= nrows) return;
  int idx = base + w;
  int start = rowptr[idx];
  int end = (idx + 1 == nkx) ? tot : rowptr[idx + 1];
  float a0 = 0.f, a1 = 0.f, a2 = 0.f, a3 = 0.f;
  float b0 = 0.f, b1 = 0.f, b2 = 0.f, b3 = 0.f;
  int n = start + q;  // this quarter's nnz stream (stride 4)
  for (; n + 4 < end; n += 8) {
    int2 c0 = sd[n], c1 = sd[n + 4];
    uint2 d0 = X64[(size_t)(c0.x & 0x1FFFF) * 16 + l4];
    uint2 d1 = X64[(size_t)(c1.x & 0x1FFFF) * 16 + l4];
    float v0 = __int_as_float(c0.y), v1 = __int_as_float(c1.y);
    a0 += v0 * bflo(d0.x); a1 += v0 * bfhi(d0.x);
    a2 += v0 * bflo(d0.y); a3 += v0 * bfhi(d0.y);
    b0 += v1 * bflo(d1.x); b1 += v1 * bfhi(d1.x);
    b2 += v1 * bflo(d1.y); b3 += v1 * bfhi(d1.y);
  }
  for (; n < end; n += 4) {
    int2 cv = sd[n];
    uint2 dv = X64[(size_t)(cv.x & 0x1FFFF) * 16 + l4];
    float vv = __int_as_float(cv.y);
    a0 += vv * bflo(dv.x); a1 += vv * bfhi(dv.x);
    a2 += vv * bflo(dv.y); a3 += vv * bfhi(dv.y);
  }
  float y0 = a0 + b0, y1 = a1 + b1, y2 = a2 + b2, y3 = a3 + b3;
  y0 += __shfl(y0, lane ^ 16); y1 += __shfl(y1, lane ^ 16);
  y2 += __shfl(y2, lane ^ 16); y3 += __shfl(y3, lane ^ 16);
  y0 += __shfl(y0, lane ^ 32); y1 += __shfl(y1, lane ^ 32);
  y2 += __shfl(y2, lane ^ 32); y3 += __shfl(y3, lane ^ 32);
  if (lane >= 16) return;
  // lane l4 holds row elements 4*l4 .. 4*l4+3
  size_t o = (size_t)w * D + 4 * l4;
  if (presid) {
    float4 p = *(float4*)&presid[o];
    p.x += y0; p.y += y1; p.z += y2; p.w += y3;
    *(float4*)&presid[o] = p;
    float4 av = *(float4*)&acc[o];
    av.x += p.x; av.y += p.y; av.z += p.z; av.w += p.w;
    *(float4*)&acc[o] = av;
    if (pm64) {
      uint2 pk;
      pk.x = (unsigned)f2bf(p.x) | ((unsigned)f2bf(p.y) << 16);
      pk.y = (unsigned)f2bf(p.z) | ((unsigned)f2bf(p.w) << 16);
      pm64[(size_t)w * 16 + l4] = pk;
    }
    if (am64) {
      uint2 ak;
      ak.x = (unsigned)f2bf(av.x) | ((unsigned)f2bf(av.y) << 16);
      ak.y = (unsigned)f2bf(av.z) | ((unsigned)f2bf(av.w) << 16);
      am64[(size_t)w * 16 + l4] = ak;
    }
  } else if (Y64) {
    uint2 pk;
    pk.x = (unsigned)f2bf(y0) | ((unsigned)f2bf(y1) << 16);
    pk.y = (unsigned)f2bf(y2) | ((unsigned)f2bf(y3) << 16);
    Y64[(size_t)w * 16 + l4] = pk;
  } else {
    float4 yv; yv.x = y0; yv.y = y1; yv.z = y2; yv.w = y3;
    *(float4*)&Yf[o] = yv;
  }
}

// a = src; b = src  (float4)
__global__ __launch_bounds__(256) void copy2_kernel(
    const float4* __restrict__ s, float4* __restrict__ a,
    float4* __restrict__ b, int n4) {
  int i = blockIdx.x * blockDim.x + threadIdx.x;
  if (i < n4) {
    float4 v = s[i];
    a[i] = v;
    b[i] = v;
  }
}

// ---------------------------------------------------------------------------
// Final pooling over bf16 table mirrors: wave per user, quarter q handles
// timesteps t=q,q+4,...; 16 lanes x uint2 = 128B row per gather. Merge via
// shfl ^16,^32; lanes 0-15 write float4 outputs. colU stays f32 (4096 rows).
// ---------------------------------------------------------------------------
__global__ __launch_bounds__(256) void final_kernel(
    const int* __restrict__ user_idx, const int* __restrict__ seq,
    const int* __restrict__ mask, const uint2* __restrict__ colP16,
    const uint2* __restrict__ transP16, const uint2* __restrict__ regP16,
    const uint2* __restrict__ catP16, const float* __restrict__ colU,
    float* __restrict__ out) {
  int lane = threadIdx.x & 63;
  int q = lane >> 4, l4 = lane & 15;
  int wid = (int)((blockIdx.x * (long)blockDim.x + threadIdx.x) >> 6);
  if (wid >= Bn) return;
  float c0 = 0.f, c1 = 0.f, c2 = 0.f, c3 = 0.f;
  float t0 = 0.f, t1 = 0.f, t2 = 0.f, t3 = 0.f;
  float r0 = 0.f, r1 = 0.f, r2 = 0.f, r3 = 0.f;
  float g0 = 0.f, g1 = 0.f, g2 = 0.f, g3 = 0.f;
  int cnt = 0;
  for (int t = q; t < Tn; t += 4) {
    int m = mask[wid * Tn + t];
    int idx = seq[wid * Tn + t];
    cnt += m;
    if (m && idx < Pn) {
      size_t ro = (size_t)idx * 16 + l4;
      uint2 dc = colP16[ro];
      uint2 dt = transP16[ro];
      uint2 dr = regP16[ro];
      uint2 dg = catP16[ro];
      c0 += bflo(dc.x); c1 += bfhi(dc.x); c2 += bflo(dc.y); c3 += bfhi(dc.y);
      t0 += bflo(dt.x); t1 += bfhi(dt.x); t2 += bflo(dt.y); t3 += bfhi(dt.y);
      r0 += bflo(dr.x); r1 += bfhi(dr.x); r2 += bflo(dr.y); r3 += bfhi(dr.y);
      g0 += bflo(dg.x); g1 += bfhi(dg.x); g2 += bflo(dg.y); g3 += bfhi(dg.y);
    }
  }
  cnt += __shfl(cnt, lane ^ 16); cnt += __shfl(cnt, lane ^ 32);
  c0 += __shfl(c0, lane ^ 16); c0 += __shfl(c0, lane ^ 32);
  c1 += __shfl(c1, lane ^ 16); c1 += __shfl(c1, lane ^ 32);
  c2 += __shfl(c2, lane ^ 16); c2 += __shfl(c2, lane ^ 32);
  c3 += __shfl(c3, lane ^ 16); c3 += __shfl(c3, lane ^ 32);
  t0 += __shfl(t0, lane ^ 16); t0 += __shfl(t0, lane ^ 32);
  t1 += __shfl(t1, lane ^ 16); t1 += __shfl(t1, lane ^ 32);
  t2 += __shfl(t2, lane ^ 16); t2 += __shfl(t2, lane ^ 32);
  t3 += __shfl(t3, lane ^ 16); t3 += __shfl(t3, lane ^ 32);
  r0 += __shfl(r0, lane ^ 16); r0 += __shfl(r0, lane ^ 32);
  r1 += __shfl(r1, lane ^ 16); r1 += __shfl(r1, lane ^ 32);
  r2 += __shfl(r2, lane ^ 16); r2 += __shfl(r2, lane ^ 32);
  r3 += __shfl(r3, lane ^ 16); r3 += __shfl(r3, lane ^ 32);
  g0 += __shfl(g0, lane ^ 16); g0 += __shfl(g0, lane ^ 32);
  g1 += __shfl(g1, lane ^ 16); g1 += __shfl(g1, lane ^ 32);
  g2 += __shfl(g2, lane ^ 16); g2 += __shfl(g2, lane ^ 32);
  g3 += __shfl(g3, lane ^ 16); g3 += __shfl(g3, lane ^ 32);
  if (lane >= 16) return;
  float dn = 1.f / (float)(cnt > 0 ? cnt : 1);
  const float inv = 1.f / 3.f;  // 1/(N_LAYERS+1), common to all four nets
  int u = user_idx[wid];
  float4 cu = *(const float4*)&colU[(size_t)u * D + 4 * l4];
  size_t ob = (size_t)wid * D + 4 * l4;
  float4 o0;
  o0.x = (cu.x + c0 * dn) * inv; o0.y = (cu.y + c1 * dn) * inv;
  o0.z = (cu.z + c2 * dn) * inv; o0.w = (cu.w + c3 * dn) * inv;
  *(float4*)&out[0 * Bn * D + ob] = o0;
  float4 o1v;
  o1v.x = t0 * dn * inv; o1v.y = t1 * dn * inv;
  o1v.z = t2 * dn * inv; o1v.w = t3 * dn * inv;
  *(float4*)&out[1 * Bn * D + ob] = o1v;
  float4 o2v;
  o2v.x = r0 * dn * inv; o2v.y = r1 * dn * inv;
  o2v.z = r2 * dn * inv; o2v.w = r3 * dn * inv;
  *(float4*)&out[2 * Bn * D + ob] = o2v;
  float4 o3v;
  o3v.x = g0 * dn * inv; o3v.y = g1 * dn * inv;
  o3v.z = g2 * dn * inv; o3v.w = g3 * dn * inv;
  *(float4*)&out[3 * Bn * D + ob] = o3v;
}

extern "C" void kernel_launch(void* const* d_in, const int* in_sizes, int n_in,
                              void* d_out, int out_size, void* d_ws,
                              size_t ws_size, hipStream_t stream) {
  (void)in_sizes; (void)n_in; (void)out_size; (void)ws_size;
  const int*   user_idx      = (const int*)d_in[0];
  const int*   user_seq      = (const int*)d_in[1];
  const int*   user_seq_mask = (const int*)d_in[2];
  const int*   col_poi_idx   = (const int*)d_in[3];
  const int*   col_user_idx  = (const int*)d_in[4];
  const float* col_vals_pe   = (const float*)d_in[5];
  const float* col_vals_ep   = (const float*)d_in[6];
  const int*   reg_poi_idx   = (const int*)d_in[7];
  const int*   reg_region_idx= (const int*)d_in[8];
  const float* reg_vals_pe   = (const float*)d_in[9];
  const float* reg_vals_ep   = (const float*)d_in[10];
  const int*   cat_poi_idx   = (const int*)d_in[11];
  const int*   cat_cat_idx   = (const int*)d_in[12];
  const float* cat_vals_pe   = (const float*)d_in[13];
  const float* cat_vals_ep   = (const float*)d_in[14];
  const int*   trans_poi_idx = (const int*)d_in[15];
  const int*   trans_edge_idx= (const int*)d_in[16];
  const float* trans_vals_tar= (const float*)d_in[17];
  const float* trans_vals_src= (const float*)d_in[18];
  const float* poi_emb       = (const float*)d_in[19];
  const float* user_emb      = (const float*)d_in[20];
  const float* region_emb    = (const float*)d_in[21];
  const float* cat_emb       = (const float*)d_in[22];
  const float* w_gate_col    = (const float*)d_in[23];
  const float* b_gate_col    = (const float*)d_in[24];
  const float* w_gate_trans  = (const float*)d_in[25];
  const float* b_gate_trans  = (const float*)d_in[26];
  const float* w_gate_reg    = (const float*)d_in[27];
  const float* b_gate_reg    = (const float*)d_in[28];
  const float* w_gate_cat    = (const float*)d_in[29];
  const float* b_gate_cat    = (const float*)d_in[30];
  const float* col_Wp = (const float*)d_in[31];
  const float* col_We = (const float*)d_in[32];
  const float* col_Wf = (const float*)d_in[33];
  const float* reg_Wp = (const float*)d_in[34];
  const float* reg_We = (const float*)d_in[35];
  const float* reg_Wf = (const float*)d_in[36];
  const float* cat_Wp = (const float*)d_in[37];
  const float* cat_We = (const float*)d_in[38];
  const float* cat_Wf = (const float*)d_in[39];

  float* ws = (float*)d_ws;
  size_t off = 0;
  auto alloc = [&](size_t n) { float* p = ws + off; off += n; return p; };
  const size_t PD = (size_t)Pn * D;
  const size_t UD = (size_t)Un * D;
  const size_t ED = (size_t)ETn * D;

  float* colP   = alloc(PD);
  float* regP   = alloc(PD);
  float* catP   = alloc(PD);
  float* transP = alloc(PD);
  float* colU   = alloc(UD);
  float* p_buf  = alloc(PD);
  float* e_buf  = alloc(UD);
  float* tmpE1  = alloc(UD);              // hetero pe-spmm out (f32, <=Un rows)
  float* acce   = alloc((size_t)Rn * D);
  float* WeWf   = alloc(D * D);
  unsigned short* tmpP16   = (unsigned short*)alloc(PD / 2);  // bf16 gather src
  unsigned short* tmpE2_16 = (unsigned short*)alloc(UD / 2);
  unsigned short* tmpE1_16 = (unsigned short*)alloc(ED / 2);  // trans hop1 out
  unsigned short* p16      = (unsigned short*)alloc(PD / 2);  // trans p mirror
  unsigned short* colP16   = (unsigned short*)alloc(PD / 2);  // acc mirrors
  unsigned short* regP16   = (unsigned short*)alloc(PD / 2);
  unsigned short* catP16   = (unsigned short*)alloc(PD / 2);
  unsigned short* transP16 = (unsigned short*)alloc(PD / 2);
  int2*  sd     = (int2*)alloc(4 * (size_t)NNZ_T);  // both dirs, 2*nnz int2
  int*   rowptr = (int*)alloc(Pn + ETn + 2);
  int*   bktcnt = (int*)alloc(4096);
  int*   bktptr = (int*)alloc(4096);
  int*   cursorB= (int*)alloc(4096);

  const int GCAP = 1024;
  const int NB2 = cdiv(Pn, 128);  // 782 poi buckets (shift 7)

  // Build exact CSR (both directions) for one graph:
  // direction-split bucket-hist -> 1-block scan -> direction-split binned
  // scatter -> refine (writes exact rowptr + reorders in place).
  auto sort2 = [&](const int* k1, const int* o1, const float* v1, int s1,
                   int nk1, const int* k2, const int* o2, const float* v2,
                   int nnz) {
    int nb1 = cdiv(nk1, 1 << s1);
    int nkb = nb1 + NB2;                 // bucket count (<= ~1800)
    int nbmax = max(nb1, NB2);
    int tot = 2 * nnz;
    hipMemsetAsync(bktcnt, 0, (size_t)nkb * sizeof(int), stream);
    int nblk = cdiv(nnz, TILE);
    hist_binned_kernel<<<2 * nblk, 1024, nbmax * 4, stream>>>(
        k1, k2, bktcnt, s1, nb1, NB2, nblk, nnz);
    scan_dual_kernel<<<1, 1024, 0, stream>>>(bktcnt, bktptr, cursorB, nkb);
    scatter_binned_kernel<<<2 * nblk, 1024, 2 * nbmax * 4, stream>>>(
        k1, o1, v1, k2, o2, v2, cursorB, sd, s1, nb1, NB2, nblk, nnz);
    refine_kernel<<<nkb, 256, 0, stream>>>(bktptr, sd, rowptr, s1, nb1, nk1,
                                           nkb, tot);
    return nk1 + Pn;  // exact key count
  };

  auto spmm = [&](int base, int nkx, int nnz2, const unsigned short* X16,
                  float* Yf, unsigned short* Y16, float* presid, float* acc,
                  unsigned short* pm16, unsigned short* am16, int nrows) {
    spmm_csr_kernel<<<cdiv(nrows, 4), 256, 0, stream>>>(
        rowptr, base, nkx, nnz2, sd, (const uint2*)X16, Yf, (uint2*)Y16,
        presid, acc, (uint2*)pm16, (uint2*)am16, nrows);
  };

  auto hetero = [&](const float* wg, const float* bg, const float* edge_emb,
                    int Ne, int s1, const int* poi_idx, const int* edge_idx,
                    const float* v_pe, const float* v_ep, const float* Wp,
                    const float* We, const float* Wf, int nnz, float* accP,
                    float* accE, unsigned short* accP16) {
    int nkx = sort2(edge_idx, poi_idx, v_pe, s1, Ne, poi_idx, edge_idx, v_ep,
                    nnz);
    gate_kernel<<<GCAP, 256, 0, stream>>>(poi_emb, wg, bg, p_buf, accP,
                                          nullptr, Pn);
    copy2_kernel<<<cdiv(Ne * D / 4, 256), 256, 0, stream>>>(
        (const float4*)edge_emb, (float4*)e_buf, (float4*)accE, Ne * D / 4);
    matmul_kernel<<<16, 256, 0, stream>>>(We, Wf + D * D, WeWf, D);  // We@Wf_bot
    for (int l = 0; l < 2; ++l) {
      matmul_bf16_kernel<<<GCAP, 256, 0, stream>>>(p_buf, Wp, tmpP16, Pn);
      spmm(0, nkx, 2 * nnz, tmpP16, tmpE1, nullptr, nullptr, nullptr, nullptr,
           nullptr, Ne);  // poi_msg (dest=edge rows)
      fused2_resid_kernel<<<min(cdiv(Ne, 4), GCAP), 256, 0, stream>>>(
          tmpE1, Wf, WeWf, tmpE2_16, e_buf, accE, Ne);
      spmm(Ne, nkx, 2 * nnz, tmpE2_16, nullptr, nullptr, p_buf, accP, nullptr,
           (l == 1) ? accP16 : nullptr, Pn);  // prop + fused residual (+mirror)
    }
  };

  // --- three hetero nets (acc scaled by 1/3 in final kernel) ---
  hetero(w_gate_col, b_gate_col, user_emb, Un, 5, col_poi_idx, col_user_idx,
         col_vals_pe, col_vals_ep, col_Wp, col_We, col_Wf, NNZ_COL, colP, colU,
         colP16);
  hetero(w_gate_reg, b_gate_reg, region_emb, Rn, 0, reg_poi_idx,
         reg_region_idx, reg_vals_pe, reg_vals_ep, reg_Wp, reg_We, reg_Wf,
         NNZ_REG, regP, acce, regP16);
  hetero(w_gate_cat, b_gate_cat, cat_emb, Cn, 0, cat_poi_idx, cat_cat_idx,
         cat_vals_pe, cat_vals_ep, cat_Wp, cat_We, cat_Wf, NNZ_CAT, catP, acce,
         catP16);

  // --- directed trans net (bf16 mirror p16 is the gather source) ---
  int nkx = sort2(trans_edge_idx, trans_poi_idx, trans_vals_tar, 6, ETn,
                  trans_poi_idx, trans_edge_idx, trans_vals_src, NNZ_T);
  gate_kernel<<<GCAP, 256, 0, stream>>>(poi_emb, w_gate_trans, b_gate_trans,
                                        p_buf, transP, p16, Pn);
  for (int l = 0; l < 2; ++l) {
    spmm(0, nkx, 2 * NNZ_T, p16, nullptr, tmpE1_16, nullptr, nullptr, nullptr,
         nullptr, ETn);  // msg_tar -> bf16
    spmm(ETn, nkx, 2 * NNZ_T, tmpE1_16, nullptr, nullptr, p_buf, transP,
         (l == 0) ? p16 : nullptr, (l == 1) ? transP16 : nullptr,
         Pn);  // msg_src + residual (+p mirror l0 / +acc mirror l1)
  }

  // --- sequence pooling + output (bf16 mirrors) ---
  final_kernel<<<cdiv(Bn * 64, 256), 256, 0, stream>>>(
      user_idx, user_seq, user_seq_mask, (const uint2*)colP16,
      (const uint2*)transP16, (const uint2*)regP16, (const uint2*)catP16,
      colU, (float*)d_out);
}